// Round 21
// baseline (57.635 us; speedup 1.0000x reference)
//
#include <hip/hip_runtime.h>
#include <hip/hip_bf16.h>

typedef __attribute__((ext_vector_type(8))) short short8;
typedef __attribute__((ext_vector_type(4))) float f32x4;

__device__ __forceinline__ unsigned short f2bf(float f){
    union { float f; unsigned u; } uf; uf.f = f;
    unsigned u = uf.u;
    u += 0x7FFFu + ((u >> 16) & 1u);   // RNE
    return (unsigned short)(u >> 16);
}
__device__ __forceinline__ int pack2(float a, float b){
    union { float f; unsigned u; } ua, ub; ua.f = a; ub.f = b;
    unsigned x = ua.u; x += 0x7FFFu + ((x >> 16) & 1u);
    unsigned y = ub.u; y += 0x7FFFu + ((y >> 16) & 1u);
    return (int)((x >> 16) | (y & 0xFFFF0000u));
}
__device__ __forceinline__ unsigned cvtpk(float lo, float hi){
    unsigned r;
    asm("v_cvt_pk_bf16_f32 %0, %1, %2" : "=v"(r) : "v"(lo), "v"(hi));
    return r;
}
__device__ __forceinline__ float fexp2(float x){
    return __builtin_amdgcn_exp2f(x);   // v_exp_f32: 2^x
}

#define N_SPATIAL 1600
#define QSCALE_LOG2E 0.25506601f   /* 32^-0.5 * log2(e), folded into q */
#define KSTR 72                    /* padded LDS row stride (u16) for K=64-chunk GEMM tiles */

// ---------------- K1 fused: [0,800) qkv GEMM (K=64 chunks) ; [800,1600) pev ----------------
__global__ __launch_bounds__(256) void k_fuse(const float* __restrict__ x,
                                              const float* __restrict__ wq,
                                              const float* __restrict__ qg,
                                              const float* __restrict__ qb,
                                              const float* __restrict__ qm,
                                              const float* __restrict__ qv,
                                              const float* __restrict__ pw,
                                              const float* __restrict__ pg,
                                              const float* __restrict__ pb,
                                              const float* __restrict__ pm,
                                              const float* __restrict__ pv,
                                              unsigned short* __restrict__ qk_t,
                                              unsigned short* __restrict__ v_mf){
    __shared__ alignas(16) char smem[20864];
    int blk = blockIdx.x;
    int tid = threadIdx.x;
    if (blk < 800){
        // ---------------- qkv GEMM, K-chunk 64 ----------------
        unsigned short* a_lds = (unsigned short*)smem;           // 64*KSTR
        unsigned short* b_lds = a_lds + 64*KSTR;                 // 64*KSTR
        int bi = blk;
        int b = bi / 200, ot = (bi/25) % 8, nt = bi % 25;
        int o0 = ot*64, n0 = nt*64;
        int w = tid>>6, lane = tid&63;
        int row = tid>>2, seg = (tid&3)*16;
        int bn = tid & 63, bc0 = (tid>>6)*16;
        int ql = lane&15, lg = lane>>4;
        f32x4 acc[4];
        #pragma unroll
        for (int t=0;t<4;t++) acc[t] = (f32x4){0.f,0.f,0.f,0.f};
        const float* asrc = wq + (size_t)(o0+row)*256 + seg;
        const float* xb = x + (size_t)b*256*N_SPATIAL + n0 + bn;
        for (int c0=0; c0<256; c0+=64){
            // A: W rows, 16 f32 -> 16 bf16 (2 b128 writes)
            float4 f0 = *reinterpret_cast<const float4*>(asrc + c0);
            float4 f1 = *reinterpret_cast<const float4*>(asrc + c0 + 4);
            float4 f2 = *reinterpret_cast<const float4*>(asrc + c0 + 8);
            float4 f3 = *reinterpret_cast<const float4*>(asrc + c0 + 12);
            int4 av0; av0.x = pack2(f0.x,f0.y); av0.y = pack2(f0.z,f0.w);
                      av0.z = pack2(f1.x,f1.y); av0.w = pack2(f1.z,f1.w);
            int4 av1; av1.x = pack2(f2.x,f2.y); av1.y = pack2(f2.z,f2.w);
                      av1.z = pack2(f3.x,f3.y); av1.w = pack2(f3.z,f3.w);
            *reinterpret_cast<int4*>(&a_lds[row*KSTR + seg])     = av0;
            *reinterpret_cast<int4*>(&a_lds[row*KSTR + seg + 8]) = av1;
            // B: x^T tile [n][c], 16 coalesced c-row reads -> 2 b128 writes
            float v0 = xb[(size_t)(c0+bc0+ 0)*N_SPATIAL];
            float v1 = xb[(size_t)(c0+bc0+ 1)*N_SPATIAL];
            float v2 = xb[(size_t)(c0+bc0+ 2)*N_SPATIAL];
            float v3 = xb[(size_t)(c0+bc0+ 3)*N_SPATIAL];
            float v4 = xb[(size_t)(c0+bc0+ 4)*N_SPATIAL];
            float v5 = xb[(size_t)(c0+bc0+ 5)*N_SPATIAL];
            float v6 = xb[(size_t)(c0+bc0+ 6)*N_SPATIAL];
            float v7 = xb[(size_t)(c0+bc0+ 7)*N_SPATIAL];
            float v8 = xb[(size_t)(c0+bc0+ 8)*N_SPATIAL];
            float v9 = xb[(size_t)(c0+bc0+ 9)*N_SPATIAL];
            float va = xb[(size_t)(c0+bc0+10)*N_SPATIAL];
            float vb = xb[(size_t)(c0+bc0+11)*N_SPATIAL];
            float vc = xb[(size_t)(c0+bc0+12)*N_SPATIAL];
            float vd = xb[(size_t)(c0+bc0+13)*N_SPATIAL];
            float ve = xb[(size_t)(c0+bc0+14)*N_SPATIAL];
            float vf = xb[(size_t)(c0+bc0+15)*N_SPATIAL];
            int4 bv0; bv0.x = pack2(v0,v1); bv0.y = pack2(v2,v3);
                      bv0.z = pack2(v4,v5); bv0.w = pack2(v6,v7);
            int4 bv1; bv1.x = pack2(v8,v9); bv1.y = pack2(va,vb);
                      bv1.z = pack2(vc,vd); bv1.w = pack2(ve,vf);
            *reinterpret_cast<int4*>(&b_lds[bn*KSTR + bc0])     = bv0;
            *reinterpret_cast<int4*>(&b_lds[bn*KSTR + bc0 + 8]) = bv1;
            __syncthreads();
            #pragma unroll
            for (int k0=0; k0<64; k0+=32){
                short8 af = *reinterpret_cast<const short8*>(&a_lds[(16*w + ql)*KSTR + k0 + lg*8]);
                #pragma unroll
                for (int t=0;t<4;t++){
                    short8 bf = *reinterpret_cast<const short8*>(&b_lds[(16*t + ql)*KSTR + k0 + lg*8]);
                    acc[t] = __builtin_amdgcn_mfma_f32_16x16x32_bf16(af, bf, acc[t], 0, 0, 0);
                }
            }
            __syncthreads();
        }
        int ob = o0 + 16*w + 4*lg;
        int grp = ob >> 5, d0 = ob & 31;
        float invr[4], b2r[4];
        #pragma unroll
        for (int r=0;r<4;r++){
            int o = ob + r;
            invr[r] = qg[o] * rsqrtf(qv[o] + 1e-5f);
            b2r[r]  = qb[o] - qm[o]*invr[r];
        }
        float qs = (ob < 256) ? QSCALE_LOG2E : 1.0f;
        unsigned short* dstb = qk_t + ((size_t)(b*16 + grp)*N_SPATIAL)*32 + d0;
        #pragma unroll
        for (int t=0;t<4;t++){
            int n = n0 + 16*t + ql;
            float y[4];
            #pragma unroll
            for (int r=0;r<4;r++){
                float z = acc[t][r]*invr[r] + b2r[r];
                y[r] = (z / (1.f + __expf(-z))) * qs;
            }
            uint2 wv = make_uint2((unsigned)pack2(y[0],y[1]), (unsigned)pack2(y[2],y[3]));
            *reinterpret_cast<uint2*>(dstb + (size_t)n*32) = wv;
        }
        return;
    }
    // ---------------- pev ----------------
    {
        float (*xs)[163] = reinterpret_cast<float(*)[163]>(smem);
        int pbi = blk - 800;              // 800 = b*200 + h*25 + kt
        int b = pbi/200, h=(pbi/25)%8, kt=pbi%25;
        int winStart = kt*64 - 48;
        const float* xbase = x + ((size_t)(b*256 + h*32))*N_SPATIAL;
        #pragma unroll
        for (int i=0;i<20;i++){
            int idx = tid + i*256;
            int row = idx / 160, col = idx - row*160;
            int n = winStart + col;
            float val = ((unsigned)n < 1600u) ? xbase[(size_t)row*N_SPATIAL + n] : 0.f;
            xs[row][col] = val;
        }
        __syncthreads();

        int f = tid>>6, lane = tid&63, ql = lane&15, lg = lane>>4;
        int d = (f>>1)*16 + ql;
        int c = h*32 + d;
        float inv = pg[c]*rsqrtf(pv[c]+1e-5f);
        float bias = pb[c]-pm[c]*inv;
        const float* w9 = pw + c*9;
        float w00=w9[0],w01=w9[1],w02=w9[2],w10=w9[3],w11=w9[4],w12=w9[5],w20=w9[6],w21=w9[7],w22=w9[8];
        const float* xr = xs[d];
        union { unsigned short u[8]; int4 i4; } vals;
        #pragma unroll
        for (int j=0;j<8;j++){
            int key = (f&1)*32 + (j>>2)*16 + 4*lg + (j&3);
            int n = kt*64 + key;
            int hh = n/40, ww = n - hh*40;
            int col = key + 48;
            float acc = 0.f;
            if (hh > 0){
                if (ww > 0)  acc += xr[col-41]*w00;
                             acc += xr[col-40]*w01;
                if (ww < 39) acc += xr[col-39]*w02;
            }
            if (ww > 0)  acc += xr[col-1]*w10;
                         acc += xr[col]*w11;
            if (ww < 39) acc += xr[col+1]*w12;
            if (hh < 39){
                if (ww > 0)  acc += xr[col+39]*w20;
                             acc += xr[col+40]*w21;
                if (ww < 39) acc += xr[col+41]*w22;
            }
            float out = xr[col] + acc*inv + bias;
            vals.u[j] = f2bf(out);
        }
        *reinterpret_cast<int4*>(v_mf + ((size_t)(pbi*4 + f)*64 + lane)*8) = vals.i4;
    }
}

// ---------------- K2: attention v7 + XCD swizzle (r13 exact) ----------------
__global__ __launch_bounds__(512) void k_attn7(const unsigned short* __restrict__ qk_t,
                                               const unsigned short* __restrict__ v_mf,
                                               unsigned short* __restrict__ ao_t){
    __shared__ alignas(16) unsigned short k_lds[3][64*40];
    __shared__ alignas(16) unsigned short v_lds[3][2048];
    int l = blockIdx.x;
    int xc = l & 7, j = l >> 3;
    int gg = xc + 8*(j/25);
    int bi = 25*gg + (j%25);
    int b = gg >> 3, h = gg & 7, qt = bi % 25;
    int tid = threadIdx.x, w = tid>>6, lane = tid&63;

    const unsigned short* ksrc = qk_t + ((size_t)(b*16+8+h)*N_SPATIAL)*32;
    const unsigned short* vms  = v_mf + (size_t)(b*200 + h*25)*2048;

    if (w < 4){
        int ql = lane&15, lg = lane>>4;
        int nq = qt*64 + w*16 + ql;
        const unsigned short* qsrc = qk_t + ((size_t)(b*16+h)*N_SPATIAL)*32;
        short8 qf = *reinterpret_cast<const short8*>(qsrc + (size_t)nq*32 + lg*8);
        f32x4 o0 = (f32x4){0.f,0.f,0.f,0.f};
        f32x4 o1 = (f32x4){0.f,0.f,0.f,0.f};
        float Sp = 0.f;

        asm volatile("" ::: "memory");
        __builtin_amdgcn_s_barrier();
        asm volatile("" ::: "memory");

        int cur = 0;
        for (int kt = 0; kt < 25; ++kt){
            const unsigned short* kb = &k_lds[cur][0];
            const unsigned short* vb = &v_lds[cur][0];
            short8 ka0 = *reinterpret_cast<const short8*>(kb + (size_t)( 0 + ql)*40 + lg*8);
            short8 ka1 = *reinterpret_cast<const short8*>(kb + (size_t)(16 + ql)*40 + lg*8);
            short8 ka2 = *reinterpret_cast<const short8*>(kb + (size_t)(32 + ql)*40 + lg*8);
            short8 ka3 = *reinterpret_cast<const short8*>(kb + (size_t)(48 + ql)*40 + lg*8);

            f32x4 z = (f32x4){0.f,0.f,0.f,0.f};
            f32x4 p0 = __builtin_amdgcn_mfma_f32_16x16x32_bf16(ka0, qf, z, 0,0,0);
            f32x4 p1 = __builtin_amdgcn_mfma_f32_16x16x32_bf16(ka1, qf, z, 0,0,0);
            f32x4 p2 = __builtin_amdgcn_mfma_f32_16x16x32_bf16(ka2, qf, z, 0,0,0);
            f32x4 p3 = __builtin_amdgcn_mfma_f32_16x16x32_bf16(ka3, qf, z, 0,0,0);

            #pragma unroll
            for (int r=0;r<4;r++){
                p0[r] = fexp2(p0[r]);
                p1[r] = fexp2(p1[r]);
                p2[r] = fexp2(p2[r]);
                p3[r] = fexp2(p3[r]);
            }
            Sp += ((p0[0]+p0[1])+(p0[2]+p0[3])) + ((p1[0]+p1[1])+(p1[2]+p1[3]))
                + ((p2[0]+p2[1])+(p2[2]+p2[3])) + ((p3[0]+p3[1])+(p3[2]+p3[3]));

            union { int4 i; short8 s8; } pb0, pb1;
            pb0.i = make_int4((int)cvtpk(p0[0],p0[1]), (int)cvtpk(p0[2],p0[3]),
                              (int)cvtpk(p1[0],p1[1]), (int)cvtpk(p1[2],p1[3]));
            pb1.i = make_int4((int)cvtpk(p2[0],p2[1]), (int)cvtpk(p2[2],p2[3]),
                              (int)cvtpk(p3[0],p3[1]), (int)cvtpk(p3[2],p3[3]));

            short8 va0 = *reinterpret_cast<const short8*>(vb +    0 + lane*8);
            short8 va1 = *reinterpret_cast<const short8*>(vb +  512 + lane*8);
            short8 va2 = *reinterpret_cast<const short8*>(vb + 1024 + lane*8);
            short8 va3 = *reinterpret_cast<const short8*>(vb + 1536 + lane*8);

            o0 = __builtin_amdgcn_mfma_f32_16x16x32_bf16(va0, pb0.s8, o0, 0,0,0);
            o0 = __builtin_amdgcn_mfma_f32_16x16x32_bf16(va1, pb1.s8, o0, 0,0,0);
            o1 = __builtin_amdgcn_mfma_f32_16x16x32_bf16(va2, pb0.s8, o1, 0,0,0);
            o1 = __builtin_amdgcn_mfma_f32_16x16x32_bf16(va3, pb1.s8, o1, 0,0,0);

            asm volatile("" ::: "memory");
            __builtin_amdgcn_s_barrier();
            asm volatile("" ::: "memory");
            cur = (cur==2) ? 0 : cur+1;
        }

        Sp += __shfl_xor(Sp, 16);
        Sp += __shfl_xor(Sp, 32);
        float inv = 1.f / Sp;
        size_t rowoff = ((size_t)b*N_SPATIAL + nq)*256 + h*32;
        uint2 w0 = make_uint2((unsigned)pack2(o0[0]*inv, o0[1]*inv),
                              (unsigned)pack2(o0[2]*inv, o0[3]*inv));
        *reinterpret_cast<uint2*>(ao_t + rowoff + 4*lg) = w0;
        uint2 w1 = make_uint2((unsigned)pack2(o1[0]*inv, o1[1]*inv),
                              (unsigned)pack2(o1[2]*inv, o1[3]*inv));
        *reinterpret_cast<uint2*>(ao_t + rowoff + 16 + 4*lg) = w1;
    } else {
        int pi = tid & 255;
        const unsigned short* kg = ksrc + pi*8;
        const unsigned short* vg = vms  + pi*8;
        unsigned short* kd = &k_lds[0][0] + (pi>>2)*40 + (pi&3)*8;
        unsigned short* vd = &v_lds[0][0] + pi*8;

        int4 a0 = *reinterpret_cast<const int4*>(kg);
        int4 b0 = *reinterpret_cast<const int4*>(vg);
        *reinterpret_cast<int4*>(kd) = a0;
        *reinterpret_cast<int4*>(vd) = b0;
        int4 a1 = *reinterpret_cast<const int4*>(kg + 2048);
        int4 b1 = *reinterpret_cast<const int4*>(vg + 2048);
        *reinterpret_cast<int4*>(kd + 2560) = a1;
        *reinterpret_cast<int4*>(vd + 2048) = b1;
        int4 hk = *reinterpret_cast<const int4*>(kg + 4096);
        int4 hv = *reinterpret_cast<const int4*>(vg + 4096);
        asm volatile("s_waitcnt lgkmcnt(0)" ::: "memory");
        __builtin_amdgcn_s_barrier();
        asm volatile("" ::: "memory");

        int wb = 2;
        for (int kt = 0; kt < 25; ++kt){
            if (kt < 23){
                *reinterpret_cast<int4*>(kd + wb*2560) = hk;
                *reinterpret_cast<int4*>(vd + wb*2048) = hv;
            }
            if (kt < 22){
                hk = *reinterpret_cast<const int4*>(kg + (size_t)(kt+3)*2048);
                hv = *reinterpret_cast<const int4*>(vg + (size_t)(kt+3)*2048);
            }
            asm volatile("s_waitcnt lgkmcnt(0)" ::: "memory");
            __builtin_amdgcn_s_barrier();
            asm volatile("" ::: "memory");
            wb = (wb==2) ? 0 : wb+1;
        }
    }
}

// ---------------- K3: proj GEMM, 64o x 32n tiles, K=64 chunks ----------------
__global__ __launch_bounds__(256) void k_proj5(const unsigned short* __restrict__ ao_t,
                                               const float* __restrict__ wp,
                                               const float* __restrict__ g,
                                               const float* __restrict__ be,
                                               const float* __restrict__ mu,
                                               const float* __restrict__ va,
                                               float* __restrict__ out){
    __shared__ alignas(16) unsigned short a_lds[64*KSTR];
    __shared__ alignas(16) unsigned short b_lds[32*KSTR];
    int bi = blockIdx.x;                      // 800 = 4b * 4ot * 50nt
    int b = bi / 200, ot = (bi/50) % 4, nt = bi % 50;
    int o0 = ot*64, n0 = nt*32;
    int tid = threadIdx.x, w = tid>>6, lane = tid&63;
    int arow = tid>>2, aseg = (tid&3)*16;
    int brow = tid>>3, bseg = (tid&7)*8;
    int ql = lane&15, lg = lane>>4;
    f32x4 acc[2];
    acc[0] = (f32x4){0.f,0.f,0.f,0.f};
    acc[1] = (f32x4){0.f,0.f,0.f,0.f};
    const float* asrc = wp + (size_t)(o0+arow)*256 + aseg;
    const unsigned short* bsrc = ao_t + ((size_t)b*N_SPATIAL + n0 + brow)*256 + bseg;
    for (int c0=0; c0<256; c0+=64){
        float4 f0 = *reinterpret_cast<const float4*>(asrc + c0);
        float4 f1 = *reinterpret_cast<const float4*>(asrc + c0 + 4);
        float4 f2 = *reinterpret_cast<const float4*>(asrc + c0 + 8);
        float4 f3 = *reinterpret_cast<const float4*>(asrc + c0 + 12);
        int4 av0; av0.x = pack2(f0.x,f0.y); av0.y = pack2(f0.z,f0.w);
                  av0.z = pack2(f1.x,f1.y); av0.w = pack2(f1.z,f1.w);
        int4 av1; av1.x = pack2(f2.x,f2.y); av1.y = pack2(f2.z,f2.w);
                  av1.z = pack2(f3.x,f3.y); av1.w = pack2(f3.z,f3.w);
        *reinterpret_cast<int4*>(&a_lds[arow*KSTR + aseg])     = av0;
        *reinterpret_cast<int4*>(&a_lds[arow*KSTR + aseg + 8]) = av1;
        *reinterpret_cast<int4*>(&b_lds[brow*KSTR + bseg]) =
            *reinterpret_cast<const int4*>(bsrc + c0);
        __syncthreads();
        #pragma unroll
        for (int k0=0; k0<64; k0+=32){
            short8 af = *reinterpret_cast<const short8*>(&a_lds[(16*w + ql)*KSTR + k0 + lg*8]);
            #pragma unroll
            for (int t=0;t<2;t++){
                short8 bf = *reinterpret_cast<const short8*>(&b_lds[(16*t + ql)*KSTR + k0 + lg*8]);
                acc[t] = __builtin_amdgcn_mfma_f32_16x16x32_bf16(af, bf, acc[t], 0, 0, 0);
            }
        }
        __syncthreads();
    }
    #pragma unroll
    for (int r=0;r<4;r++){
        int o = o0 + 16*w + lg*4 + r;
        float inv = g[o] * rsqrtf(va[o] + 1e-5f);
        float b2  = be[o] - mu[o]*inv;
        float* dst = out + ((size_t)(b*256 + o))*N_SPATIAL;
        #pragma unroll
        for (int t=0;t<2;t++){
            int n = n0 + 16*t + ql;
            float z = acc[t][r]*inv + b2;
            float y = z / (1.f + __expf(-z));
            dst[n] = y;
        }
    }
}

extern "C" void kernel_launch(void* const* d_in, const int* in_sizes, int n_in,
                              void* d_out, int out_size, void* d_ws, size_t ws_size,
                              hipStream_t stream) {
    const float* x      = (const float*)d_in[0];
    const float* qkv_w  = (const float*)d_in[1];
    const float* qkv_g  = (const float*)d_in[2];
    const float* qkv_b  = (const float*)d_in[3];
    const float* qkv_m  = (const float*)d_in[4];
    const float* qkv_v  = (const float*)d_in[5];
    const float* proj_w = (const float*)d_in[6];
    const float* proj_g = (const float*)d_in[7];
    const float* proj_b = (const float*)d_in[8];
    const float* proj_m = (const float*)d_in[9];
    const float* proj_v = (const float*)d_in[10];
    const float* pe_w   = (const float*)d_in[11];
    const float* pe_g   = (const float*)d_in[12];
    const float* pe_b   = (const float*)d_in[13];
    const float* pe_m   = (const float*)d_in[14];
    const float* pe_v   = (const float*)d_in[15];

    char* ws = (char*)d_ws;
    unsigned short* v_mf = (unsigned short*)(ws);                 // 3,276,800
    unsigned short* qk_t = (unsigned short*)(ws + 3276800);       // 6,553,600
    unsigned short* ao_t = (unsigned short*)(ws + 9830400);       // 3,276,800
    float* outp = (float*)d_out;

    k_fuse <<<1600,256, 0, stream>>>(x, qkv_w, qkv_g, qkv_b, qkv_m, qkv_v,
                                     pe_w, pe_g, pe_b, pe_m, pe_v, qk_t, v_mf);
    k_attn7<<<800, 512, 0, stream>>>(qk_t, v_mf, ao_t);
    k_proj5<<<800, 256, 0, stream>>>(ao_t, proj_w, proj_g, proj_b, proj_m, proj_v, outp);
}

// Round 22
// 54.344 us; speedup vs baseline: 1.0606x; 1.0606x over previous
//
#include <hip/hip_runtime.h>
#include <hip/hip_bf16.h>

typedef __attribute__((ext_vector_type(8))) short short8;
typedef __attribute__((ext_vector_type(4))) float f32x4;

__device__ __forceinline__ unsigned short f2bf(float f){
    union { float f; unsigned u; } uf; uf.f = f;
    unsigned u = uf.u;
    u += 0x7FFFu + ((u >> 16) & 1u);   // RNE
    return (unsigned short)(u >> 16);
}
__device__ __forceinline__ int pack2(float a, float b){
    union { float f; unsigned u; } ua, ub; ua.f = a; ub.f = b;
    unsigned x = ua.u; x += 0x7FFFu + ((x >> 16) & 1u);
    unsigned y = ub.u; y += 0x7FFFu + ((y >> 16) & 1u);
    return (int)((x >> 16) | (y & 0xFFFF0000u));
}
__device__ __forceinline__ unsigned cvtpk(float lo, float hi){
    unsigned r;
    asm("v_cvt_pk_bf16_f32 %0, %1, %2" : "=v"(r) : "v"(lo), "v"(hi));
    return r;
}
__device__ __forceinline__ float fexp2(float x){
    return __builtin_amdgcn_exp2f(x);   // v_exp_f32: 2^x
}

#define N_SPATIAL 1600
#define QSCALE_LOG2E 0.25506601f   /* 32^-0.5 * log2(e), folded into q */
#define LSTR 40                    /* padded LDS row stride (u16) for GEMM tiles */

// ---------------- K1 fused: [0,800) qkv GEMM (direct-x staging) ; [800,1600) pev ----------------
__global__ __launch_bounds__(256) void k_fuse(const float* __restrict__ x,
                                              const float* __restrict__ wq,
                                              const float* __restrict__ qg,
                                              const float* __restrict__ qb,
                                              const float* __restrict__ qm,
                                              const float* __restrict__ qv,
                                              const float* __restrict__ pw,
                                              const float* __restrict__ pg,
                                              const float* __restrict__ pb,
                                              const float* __restrict__ pm,
                                              const float* __restrict__ pv,
                                              unsigned short* __restrict__ qk_t,
                                              unsigned short* __restrict__ v_mf){
    __shared__ alignas(16) char smem[20864];
    int blk = blockIdx.x;
    int tid = threadIdx.x;
    if (blk < 800){
        // ---------------- qkv GEMM ----------------
        unsigned short* a_lds = (unsigned short*)smem;           // 64*LSTR
        unsigned short* b_lds = a_lds + 64*LSTR;                 // 64*LSTR
        int bi = blk;
        int b = bi / 200, ot = (bi/25) % 8, nt = bi % 25;
        int o0 = ot*64, n0 = nt*64;
        int w = tid>>6, lane = tid&63;
        int row = tid>>2, col8 = (tid&3)*8;
        int bn = tid & 63, bc0 = (tid>>6)*8;
        int ql = lane&15, lg = lane>>4;
        f32x4 acc[4];
        #pragma unroll
        for (int t=0;t<4;t++) acc[t] = (f32x4){0.f,0.f,0.f,0.f};
        const float* asrc = wq + (size_t)(o0+row)*256 + col8;
        const float* xb = x + (size_t)b*256*N_SPATIAL + n0 + bn;
        for (int k0=0; k0<256; k0+=32){
            float4 f0 = *reinterpret_cast<const float4*>(asrc + k0);
            float4 f1 = *reinterpret_cast<const float4*>(asrc + k0 + 4);
            int4 av; av.x = pack2(f0.x,f0.y); av.y = pack2(f0.z,f0.w);
                     av.z = pack2(f1.x,f1.y); av.w = pack2(f1.z,f1.w);
            *reinterpret_cast<int4*>(&a_lds[row*LSTR + col8]) = av;
            float v0 = xb[(size_t)(k0+bc0+0)*N_SPATIAL];
            float v1 = xb[(size_t)(k0+bc0+1)*N_SPATIAL];
            float v2 = xb[(size_t)(k0+bc0+2)*N_SPATIAL];
            float v3 = xb[(size_t)(k0+bc0+3)*N_SPATIAL];
            float v4 = xb[(size_t)(k0+bc0+4)*N_SPATIAL];
            float v5 = xb[(size_t)(k0+bc0+5)*N_SPATIAL];
            float v6 = xb[(size_t)(k0+bc0+6)*N_SPATIAL];
            float v7 = xb[(size_t)(k0+bc0+7)*N_SPATIAL];
            int4 bv; bv.x = pack2(v0,v1); bv.y = pack2(v2,v3);
                     bv.z = pack2(v4,v5); bv.w = pack2(v6,v7);
            *reinterpret_cast<int4*>(&b_lds[bn*LSTR + bc0]) = bv;
            __syncthreads();
            short8 af = *reinterpret_cast<const short8*>(&a_lds[(16*w + ql)*LSTR + lg*8]);
            #pragma unroll
            for (int t=0;t<4;t++){
                short8 bf = *reinterpret_cast<const short8*>(&b_lds[(16*t + ql)*LSTR + lg*8]);
                acc[t] = __builtin_amdgcn_mfma_f32_16x16x32_bf16(af, bf, acc[t], 0, 0, 0);
            }
            __syncthreads();
        }
        int ob = o0 + 16*w + 4*lg;
        int grp = ob >> 5, d0 = ob & 31;
        float invr[4], b2r[4];
        #pragma unroll
        for (int r=0;r<4;r++){
            int o = ob + r;
            invr[r] = qg[o] * rsqrtf(qv[o] + 1e-5f);
            b2r[r]  = qb[o] - qm[o]*invr[r];
        }
        float qs = (ob < 256) ? QSCALE_LOG2E : 1.0f;
        unsigned short* dstb = qk_t + ((size_t)(b*16 + grp)*N_SPATIAL)*32 + d0;
        #pragma unroll
        for (int t=0;t<4;t++){
            int n = n0 + 16*t + ql;
            float y[4];
            #pragma unroll
            for (int r=0;r<4;r++){
                float z = acc[t][r]*invr[r] + b2r[r];
                y[r] = (z / (1.f + __expf(-z))) * qs;
            }
            uint2 wv = make_uint2((unsigned)pack2(y[0],y[1]), (unsigned)pack2(y[2],y[3]));
            *reinterpret_cast<uint2*>(dstb + (size_t)n*32) = wv;
        }
        return;
    }
    // ---------------- pev ----------------
    {
        float (*xs)[163] = reinterpret_cast<float(*)[163]>(smem);
        int pbi = blk - 800;              // 800 = b*200 + h*25 + kt
        int b = pbi/200, h=(pbi/25)%8, kt=pbi%25;
        int winStart = kt*64 - 48;
        const float* xbase = x + ((size_t)(b*256 + h*32))*N_SPATIAL;
        #pragma unroll
        for (int i=0;i<20;i++){
            int idx = tid + i*256;
            int row = idx / 160, col = idx - row*160;
            int n = winStart + col;
            float val = ((unsigned)n < 1600u) ? xbase[(size_t)row*N_SPATIAL + n] : 0.f;
            xs[row][col] = val;
        }
        __syncthreads();

        int f = tid>>6, lane = tid&63, ql = lane&15, lg = lane>>4;
        int d = (f>>1)*16 + ql;
        int c = h*32 + d;
        float inv = pg[c]*rsqrtf(pv[c]+1e-5f);
        float bias = pb[c]-pm[c]*inv;
        const float* w9 = pw + c*9;
        float w00=w9[0],w01=w9[1],w02=w9[2],w10=w9[3],w11=w9[4],w12=w9[5],w20=w9[6],w21=w9[7],w22=w9[8];
        const float* xr = xs[d];
        union { unsigned short u[8]; int4 i4; } vals;
        #pragma unroll
        for (int j=0;j<8;j++){
            int key = (f&1)*32 + (j>>2)*16 + 4*lg + (j&3);
            int n = kt*64 + key;
            int hh = n/40, ww = n - hh*40;
            int col = key + 48;
            float acc = 0.f;
            if (hh > 0){
                if (ww > 0)  acc += xr[col-41]*w00;
                             acc += xr[col-40]*w01;
                if (ww < 39) acc += xr[col-39]*w02;
            }
            if (ww > 0)  acc += xr[col-1]*w10;
                         acc += xr[col]*w11;
            if (ww < 39) acc += xr[col+1]*w12;
            if (hh < 39){
                if (ww > 0)  acc += xr[col+39]*w20;
                             acc += xr[col+40]*w21;
                if (ww < 39) acc += xr[col+41]*w22;
            }
            float out = xr[col] + acc*inv + bias;
            vals.u[j] = f2bf(out);
        }
        *reinterpret_cast<int4*>(v_mf + ((size_t)(pbi*4 + f)*64 + lane)*8) = vals.i4;
    }
}

// ---------------- K2: attention v7 + XCD swizzle (r13 exact) ----------------
__global__ __launch_bounds__(512) void k_attn7(const unsigned short* __restrict__ qk_t,
                                               const unsigned short* __restrict__ v_mf,
                                               unsigned short* __restrict__ ao_t){
    __shared__ alignas(16) unsigned short k_lds[3][64*40];
    __shared__ alignas(16) unsigned short v_lds[3][2048];
    int l = blockIdx.x;
    int xc = l & 7, j = l >> 3;
    int gg = xc + 8*(j/25);
    int bi = 25*gg + (j%25);
    int b = gg >> 3, h = gg & 7, qt = bi % 25;
    int tid = threadIdx.x, w = tid>>6, lane = tid&63;

    const unsigned short* ksrc = qk_t + ((size_t)(b*16+8+h)*N_SPATIAL)*32;
    const unsigned short* vms  = v_mf + (size_t)(b*200 + h*25)*2048;

    if (w < 4){
        int ql = lane&15, lg = lane>>4;
        int nq = qt*64 + w*16 + ql;
        const unsigned short* qsrc = qk_t + ((size_t)(b*16+h)*N_SPATIAL)*32;
        short8 qf = *reinterpret_cast<const short8*>(qsrc + (size_t)nq*32 + lg*8);
        f32x4 o0 = (f32x4){0.f,0.f,0.f,0.f};
        f32x4 o1 = (f32x4){0.f,0.f,0.f,0.f};
        float Sp = 0.f;

        asm volatile("" ::: "memory");
        __builtin_amdgcn_s_barrier();
        asm volatile("" ::: "memory");

        int cur = 0;
        for (int kt = 0; kt < 25; ++kt){
            const unsigned short* kb = &k_lds[cur][0];
            const unsigned short* vb = &v_lds[cur][0];
            short8 ka0 = *reinterpret_cast<const short8*>(kb + (size_t)( 0 + ql)*40 + lg*8);
            short8 ka1 = *reinterpret_cast<const short8*>(kb + (size_t)(16 + ql)*40 + lg*8);
            short8 ka2 = *reinterpret_cast<const short8*>(kb + (size_t)(32 + ql)*40 + lg*8);
            short8 ka3 = *reinterpret_cast<const short8*>(kb + (size_t)(48 + ql)*40 + lg*8);

            f32x4 z = (f32x4){0.f,0.f,0.f,0.f};
            f32x4 p0 = __builtin_amdgcn_mfma_f32_16x16x32_bf16(ka0, qf, z, 0,0,0);
            f32x4 p1 = __builtin_amdgcn_mfma_f32_16x16x32_bf16(ka1, qf, z, 0,0,0);
            f32x4 p2 = __builtin_amdgcn_mfma_f32_16x16x32_bf16(ka2, qf, z, 0,0,0);
            f32x4 p3 = __builtin_amdgcn_mfma_f32_16x16x32_bf16(ka3, qf, z, 0,0,0);

            #pragma unroll
            for (int r=0;r<4;r++){
                p0[r] = fexp2(p0[r]);
                p1[r] = fexp2(p1[r]);
                p2[r] = fexp2(p2[r]);
                p3[r] = fexp2(p3[r]);
            }
            Sp += ((p0[0]+p0[1])+(p0[2]+p0[3])) + ((p1[0]+p1[1])+(p1[2]+p1[3]))
                + ((p2[0]+p2[1])+(p2[2]+p2[3])) + ((p3[0]+p3[1])+(p3[2]+p3[3]));

            union { int4 i; short8 s8; } pb0, pb1;
            pb0.i = make_int4((int)cvtpk(p0[0],p0[1]), (int)cvtpk(p0[2],p0[3]),
                              (int)cvtpk(p1[0],p1[1]), (int)cvtpk(p1[2],p1[3]));
            pb1.i = make_int4((int)cvtpk(p2[0],p2[1]), (int)cvtpk(p2[2],p2[3]),
                              (int)cvtpk(p3[0],p3[1]), (int)cvtpk(p3[2],p3[3]));

            short8 va0 = *reinterpret_cast<const short8*>(vb +    0 + lane*8);
            short8 va1 = *reinterpret_cast<const short8*>(vb +  512 + lane*8);
            short8 va2 = *reinterpret_cast<const short8*>(vb + 1024 + lane*8);
            short8 va3 = *reinterpret_cast<const short8*>(vb + 1536 + lane*8);

            o0 = __builtin_amdgcn_mfma_f32_16x16x32_bf16(va0, pb0.s8, o0, 0,0,0);
            o0 = __builtin_amdgcn_mfma_f32_16x16x32_bf16(va1, pb1.s8, o0, 0,0,0);
            o1 = __builtin_amdgcn_mfma_f32_16x16x32_bf16(va2, pb0.s8, o1, 0,0,0);
            o1 = __builtin_amdgcn_mfma_f32_16x16x32_bf16(va3, pb1.s8, o1, 0,0,0);

            asm volatile("" ::: "memory");
            __builtin_amdgcn_s_barrier();
            asm volatile("" ::: "memory");
            cur = (cur==2) ? 0 : cur+1;
        }

        Sp += __shfl_xor(Sp, 16);
        Sp += __shfl_xor(Sp, 32);
        float inv = 1.f / Sp;
        size_t rowoff = ((size_t)b*N_SPATIAL + nq)*256 + h*32;
        uint2 w0 = make_uint2((unsigned)pack2(o0[0]*inv, o0[1]*inv),
                              (unsigned)pack2(o0[2]*inv, o0[3]*inv));
        *reinterpret_cast<uint2*>(ao_t + rowoff + 4*lg) = w0;
        uint2 w1 = make_uint2((unsigned)pack2(o1[0]*inv, o1[1]*inv),
                              (unsigned)pack2(o1[2]*inv, o1[3]*inv));
        *reinterpret_cast<uint2*>(ao_t + rowoff + 16 + 4*lg) = w1;
    } else {
        int pi = tid & 255;
        const unsigned short* kg = ksrc + pi*8;
        const unsigned short* vg = vms  + pi*8;
        unsigned short* kd = &k_lds[0][0] + (pi>>2)*40 + (pi&3)*8;
        unsigned short* vd = &v_lds[0][0] + pi*8;

        int4 a0 = *reinterpret_cast<const int4*>(kg);
        int4 b0 = *reinterpret_cast<const int4*>(vg);
        *reinterpret_cast<int4*>(kd) = a0;
        *reinterpret_cast<int4*>(vd) = b0;
        int4 a1 = *reinterpret_cast<const int4*>(kg + 2048);
        int4 b1 = *reinterpret_cast<const int4*>(vg + 2048);
        *reinterpret_cast<int4*>(kd + 2560) = a1;
        *reinterpret_cast<int4*>(vd + 2048) = b1;
        int4 hk = *reinterpret_cast<const int4*>(kg + 4096);
        int4 hv = *reinterpret_cast<const int4*>(vg + 4096);
        asm volatile("s_waitcnt lgkmcnt(0)" ::: "memory");
        __builtin_amdgcn_s_barrier();
        asm volatile("" ::: "memory");

        int wb = 2;
        for (int kt = 0; kt < 25; ++kt){
            if (kt < 23){
                *reinterpret_cast<int4*>(kd + wb*2560) = hk;
                *reinterpret_cast<int4*>(vd + wb*2048) = hv;
            }
            if (kt < 22){
                hk = *reinterpret_cast<const int4*>(kg + (size_t)(kt+3)*2048);
                hv = *reinterpret_cast<const int4*>(vg + (size_t)(kt+3)*2048);
            }
            asm volatile("s_waitcnt lgkmcnt(0)" ::: "memory");
            __builtin_amdgcn_s_barrier();
            asm volatile("" ::: "memory");
            wb = (wb==2) ? 0 : wb+1;
        }
    }
}

// ---------------- K3: proj GEMM, 64o x 32n tiles (800 blocks), padded LDS ----------------
__global__ __launch_bounds__(256) void k_proj4(const unsigned short* __restrict__ ao_t,
                                               const float* __restrict__ wp,
                                               const float* __restrict__ g,
                                               const float* __restrict__ be,
                                               const float* __restrict__ mu,
                                               const float* __restrict__ va,
                                               float* __restrict__ out){
    __shared__ alignas(16) unsigned short a_lds[64*LSTR];
    __shared__ alignas(16) unsigned short b_lds[32*LSTR];
    int bi = blockIdx.x;                      // 800 = 4b * 4ot * 50nt
    int b = bi / 200, ot = (bi/50) % 4, nt = bi % 50;
    int o0 = ot*64, n0 = nt*32;
    int tid = threadIdx.x, w = tid>>6, lane = tid&63;
    int arow = tid>>2, acol8 = (tid&3)*8;
    int brow = tid>>3, bcol4 = (tid&7)*4;
    int ql = lane&15, lg = lane>>4;
    f32x4 acc[2];
    acc[0] = (f32x4){0.f,0.f,0.f,0.f};
    acc[1] = (f32x4){0.f,0.f,0.f,0.f};
    const float* asrc = wp + (size_t)(o0+arow)*256 + acol8;
    const unsigned short* bsrc = ao_t + ((size_t)b*N_SPATIAL + n0 + brow)*256 + bcol4;
    for (int k0=0; k0<256; k0+=32){
        float4 f0 = *reinterpret_cast<const float4*>(asrc + k0);
        float4 f1 = *reinterpret_cast<const float4*>(asrc + k0 + 4);
        int4 av; av.x = pack2(f0.x,f0.y); av.y = pack2(f0.z,f0.w);
                 av.z = pack2(f1.x,f1.y); av.w = pack2(f1.z,f1.w);
        *reinterpret_cast<int4*>(&a_lds[arow*LSTR + acol8]) = av;
        *reinterpret_cast<uint2*>(&b_lds[brow*LSTR + bcol4]) = *reinterpret_cast<const uint2*>(bsrc + k0);
        __syncthreads();
        short8 af = *reinterpret_cast<const short8*>(&a_lds[(16*w + ql)*LSTR + lg*8]);
        #pragma unroll
        for (int t=0;t<2;t++){
            short8 bf = *reinterpret_cast<const short8*>(&b_lds[(16*t + ql)*LSTR + lg*8]);
            acc[t] = __builtin_amdgcn_mfma_f32_16x16x32_bf16(af, bf, acc[t], 0, 0, 0);
        }
        __syncthreads();
    }
    #pragma unroll
    for (int r=0;r<4;r++){
        int o = o0 + 16*w + lg*4 + r;
        float inv = g[o] * rsqrtf(va[o] + 1e-5f);
        float b2  = be[o] - mu[o]*inv;
        float* dst = out + ((size_t)(b*256 + o))*N_SPATIAL;
        #pragma unroll
        for (int t=0;t<2;t++){
            int n = n0 + 16*t + ql;
            float z = acc[t][r]*inv + b2;
            float y = z / (1.f + __expf(-z));
            dst[n] = y;
        }
    }
}

extern "C" void kernel_launch(void* const* d_in, const int* in_sizes, int n_in,
                              void* d_out, int out_size, void* d_ws, size_t ws_size,
                              hipStream_t stream) {
    const float* x      = (const float*)d_in[0];
    const float* qkv_w  = (const float*)d_in[1];
    const float* qkv_g  = (const float*)d_in[2];
    const float* qkv_b  = (const float*)d_in[3];
    const float* qkv_m  = (const float*)d_in[4];
    const float* qkv_v  = (const float*)d_in[5];
    const float* proj_w = (const float*)d_in[6];
    const float* proj_g = (const float*)d_in[7];
    const float* proj_b = (const float*)d_in[8];
    const float* proj_m = (const float*)d_in[9];
    const float* proj_v = (const float*)d_in[10];
    const float* pe_w   = (const float*)d_in[11];
    const float* pe_g   = (const float*)d_in[12];
    const float* pe_b   = (const float*)d_in[13];
    const float* pe_m   = (const float*)d_in[14];
    const float* pe_v   = (const float*)d_in[15];

    char* ws = (char*)d_ws;
    unsigned short* v_mf = (unsigned short*)(ws);                 // 3,276,800
    unsigned short* qk_t = (unsigned short*)(ws + 3276800);       // 6,553,600
    unsigned short* ao_t = (unsigned short*)(ws + 9830400);       // 3,276,800
    float* outp = (float*)d_out;

    k_fuse <<<1600,256, 0, stream>>>(x, qkv_w, qkv_g, qkv_b, qkv_m, qkv_v,
                                     pe_w, pe_g, pe_b, pe_m, pe_v, qk_t, v_mf);
    k_attn7<<<800, 512, 0, stream>>>(qk_t, v_mf, ao_t);
    k_proj4<<<800, 256, 0, stream>>>(ao_t, proj_w, proj_g, proj_b, proj_m, proj_v, outp);
}

// Round 23
// 52.160 us; speedup vs baseline: 1.1050x; 1.0419x over previous
//
#include <hip/hip_runtime.h>
#include <hip/hip_bf16.h>

typedef __attribute__((ext_vector_type(8))) short short8;
typedef __attribute__((ext_vector_type(4))) float f32x4;

__device__ __forceinline__ unsigned short f2bf(float f){
    union { float f; unsigned u; } uf; uf.f = f;
    unsigned u = uf.u;
    u += 0x7FFFu + ((u >> 16) & 1u);   // RNE
    return (unsigned short)(u >> 16);
}
__device__ __forceinline__ int pack2(float a, float b){
    union { float f; unsigned u; } ua, ub; ua.f = a; ub.f = b;
    unsigned x = ua.u; x += 0x7FFFu + ((x >> 16) & 1u);
    unsigned y = ub.u; y += 0x7FFFu + ((y >> 16) & 1u);
    return (int)((x >> 16) | (y & 0xFFFF0000u));
}
__device__ __forceinline__ unsigned cvtpk(float lo, float hi){
    unsigned r;
    asm("v_cvt_pk_bf16_f32 %0, %1, %2" : "=v"(r) : "v"(lo), "v"(hi));
    return r;
}
__device__ __forceinline__ float fexp2(float x){
    return __builtin_amdgcn_exp2f(x);   // v_exp_f32: 2^x
}

#define N_SPATIAL 1600
#define QSCALE_LOG2E 0.25506601f   /* 32^-0.5 * log2(e), folded into q */
#define LSTR 40                    /* padded LDS row stride (u16) for GEMM tiles */

// ---------------- K1 fused: [0,832) qkv GEMM (XCD-grouped by (b,nt)) ; [832,1632) pev (XCD-grouped by (b,h)) ----------------
__global__ __launch_bounds__(256) void k_fuse(const float* __restrict__ x,
                                              const float* __restrict__ wq,
                                              const float* __restrict__ qg,
                                              const float* __restrict__ qb,
                                              const float* __restrict__ qm,
                                              const float* __restrict__ qv,
                                              const float* __restrict__ pw,
                                              const float* __restrict__ pg,
                                              const float* __restrict__ pb,
                                              const float* __restrict__ pm,
                                              const float* __restrict__ pv,
                                              unsigned short* __restrict__ qk_t,
                                              unsigned short* __restrict__ v_mf){
    __shared__ alignas(16) char smem[20864];
    int blk = blockIdx.x;
    int tid = threadIdx.x;
    if (blk < 832){
        // ---------------- qkv GEMM ----------------
        // XCD swizzle: the 8 ot-blocks of one (b,nt) share blockIdx%8 -> one XCD L2
        int low3 = blk & 7, inner = blk >> 3;
        int ot = inner & 7, ghi = inner >> 3;
        int g = ghi*8 + low3;
        if (g >= 100) return;            // 32 dead slots
        int b = g/25, nt = g%25;
        int o0 = ot*64, n0 = nt*64;

        unsigned short* a_lds = (unsigned short*)smem;           // 64*LSTR
        unsigned short* b_lds = a_lds + 64*LSTR;                 // 64*LSTR
        int w = tid>>6, lane = tid&63;
        int row = tid>>2, col8 = (tid&3)*8;
        int bn = tid & 63, bc0 = (tid>>6)*8;
        int ql = lane&15, lg = lane>>4;
        f32x4 acc[4];
        #pragma unroll
        for (int t=0;t<4;t++) acc[t] = (f32x4){0.f,0.f,0.f,0.f};
        const float* asrc = wq + (size_t)(o0+row)*256 + col8;
        const float* xb = x + (size_t)b*256*N_SPATIAL + n0 + bn;
        for (int k0=0; k0<256; k0+=32){
            float4 f0 = *reinterpret_cast<const float4*>(asrc + k0);
            float4 f1 = *reinterpret_cast<const float4*>(asrc + k0 + 4);
            int4 av; av.x = pack2(f0.x,f0.y); av.y = pack2(f0.z,f0.w);
                     av.z = pack2(f1.x,f1.y); av.w = pack2(f1.z,f1.w);
            *reinterpret_cast<int4*>(&a_lds[row*LSTR + col8]) = av;
            float v0 = xb[(size_t)(k0+bc0+0)*N_SPATIAL];
            float v1 = xb[(size_t)(k0+bc0+1)*N_SPATIAL];
            float v2 = xb[(size_t)(k0+bc0+2)*N_SPATIAL];
            float v3 = xb[(size_t)(k0+bc0+3)*N_SPATIAL];
            float v4 = xb[(size_t)(k0+bc0+4)*N_SPATIAL];
            float v5 = xb[(size_t)(k0+bc0+5)*N_SPATIAL];
            float v6 = xb[(size_t)(k0+bc0+6)*N_SPATIAL];
            float v7 = xb[(size_t)(k0+bc0+7)*N_SPATIAL];
            int4 bv; bv.x = pack2(v0,v1); bv.y = pack2(v2,v3);
                     bv.z = pack2(v4,v5); bv.w = pack2(v6,v7);
            *reinterpret_cast<int4*>(&b_lds[bn*LSTR + bc0]) = bv;
            __syncthreads();
            short8 af = *reinterpret_cast<const short8*>(&a_lds[(16*w + ql)*LSTR + lg*8]);
            #pragma unroll
            for (int t=0;t<4;t++){
                short8 bf = *reinterpret_cast<const short8*>(&b_lds[(16*t + ql)*LSTR + lg*8]);
                acc[t] = __builtin_amdgcn_mfma_f32_16x16x32_bf16(af, bf, acc[t], 0, 0, 0);
            }
            __syncthreads();
        }
        int ob = o0 + 16*w + 4*lg;
        int grp = ob >> 5, d0 = ob & 31;
        float invr[4], b2r[4];
        #pragma unroll
        for (int r=0;r<4;r++){
            int o = ob + r;
            invr[r] = qg[o] * rsqrtf(qv[o] + 1e-5f);
            b2r[r]  = qb[o] - qm[o]*invr[r];
        }
        float qs = (ob < 256) ? QSCALE_LOG2E : 1.0f;
        unsigned short* dstb = qk_t + ((size_t)(b*16 + grp)*N_SPATIAL)*32 + d0;
        #pragma unroll
        for (int t=0;t<4;t++){
            int n = n0 + 16*t + ql;
            float y[4];
            #pragma unroll
            for (int r=0;r<4;r++){
                float z = acc[t][r]*invr[r] + b2r[r];
                y[r] = (z / (1.f + __expf(-z))) * qs;
            }
            uint2 wv = make_uint2((unsigned)pack2(y[0],y[1]), (unsigned)pack2(y[2],y[3]));
            *reinterpret_cast<uint2*>(dstb + (size_t)n*32) = wv;
        }
        return;
    }
    // ---------------- pev ----------------
    {
        // XCD swizzle: the 25 kt-blocks of one (b,h) share blockIdx%8 -> one XCD L2
        int pl = blk - 832;               // [0,800)
        int low3 = pl & 7, inner = pl >> 3;
        int kt = inner % 25, gph = (inner/25)*8 + low3;
        int b = gph >> 3, h = gph & 7;
        int pbi = b*200 + h*25 + kt;      // original output index

        float (*xs)[163] = reinterpret_cast<float(*)[163]>(smem);
        int winStart = kt*64 - 48;
        const float* xbase = x + ((size_t)(b*256 + h*32))*N_SPATIAL;
        #pragma unroll
        for (int i=0;i<20;i++){
            int idx = tid + i*256;
            int row = idx / 160, col = idx - row*160;
            int n = winStart + col;
            float val = ((unsigned)n < 1600u) ? xbase[(size_t)row*N_SPATIAL + n] : 0.f;
            xs[row][col] = val;
        }
        __syncthreads();

        int f = tid>>6, lane = tid&63, ql = lane&15, lg = lane>>4;
        int d = (f>>1)*16 + ql;
        int c = h*32 + d;
        float inv = pg[c]*rsqrtf(pv[c]+1e-5f);
        float bias = pb[c]-pm[c]*inv;
        const float* w9 = pw + c*9;
        float w00=w9[0],w01=w9[1],w02=w9[2],w10=w9[3],w11=w9[4],w12=w9[5],w20=w9[6],w21=w9[7],w22=w9[8];
        const float* xr = xs[d];
        union { unsigned short u[8]; int4 i4; } vals;
        #pragma unroll
        for (int j=0;j<8;j++){
            int key = (f&1)*32 + (j>>2)*16 + 4*lg + (j&3);
            int n = kt*64 + key;
            int hh = n/40, ww = n - hh*40;
            int col = key + 48;
            float acc = 0.f;
            if (hh > 0){
                if (ww > 0)  acc += xr[col-41]*w00;
                             acc += xr[col-40]*w01;
                if (ww < 39) acc += xr[col-39]*w02;
            }
            if (ww > 0)  acc += xr[col-1]*w10;
                         acc += xr[col]*w11;
            if (ww < 39) acc += xr[col+1]*w12;
            if (hh < 39){
                if (ww > 0)  acc += xr[col+39]*w20;
                             acc += xr[col+40]*w21;
                if (ww < 39) acc += xr[col+41]*w22;
            }
            float out = xr[col] + acc*inv + bias;
            vals.u[j] = f2bf(out);
        }
        *reinterpret_cast<int4*>(v_mf + ((size_t)(pbi*4 + f)*64 + lane)*8) = vals.i4;
    }
}

// ---------------- K2: attention v7 + XCD swizzle + T5 setprio ----------------
__global__ __launch_bounds__(512) void k_attn7(const unsigned short* __restrict__ qk_t,
                                               const unsigned short* __restrict__ v_mf,
                                               unsigned short* __restrict__ ao_t){
    __shared__ alignas(16) unsigned short k_lds[3][64*40];
    __shared__ alignas(16) unsigned short v_lds[3][2048];
    int l = blockIdx.x;
    int xc = l & 7, j = l >> 3;
    int gg = xc + 8*(j/25);
    int bi = 25*gg + (j%25);
    int b = gg >> 3, h = gg & 7, qt = bi % 25;
    int tid = threadIdx.x, w = tid>>6, lane = tid&63;

    const unsigned short* ksrc = qk_t + ((size_t)(b*16+8+h)*N_SPATIAL)*32;
    const unsigned short* vms  = v_mf + (size_t)(b*200 + h*25)*2048;

    if (w < 4){
        int ql = lane&15, lg = lane>>4;
        int nq = qt*64 + w*16 + ql;
        const unsigned short* qsrc = qk_t + ((size_t)(b*16+h)*N_SPATIAL)*32;
        short8 qf = *reinterpret_cast<const short8*>(qsrc + (size_t)nq*32 + lg*8);
        f32x4 o0 = (f32x4){0.f,0.f,0.f,0.f};
        f32x4 o1 = (f32x4){0.f,0.f,0.f,0.f};
        float Sp = 0.f;

        asm volatile("" ::: "memory");
        __builtin_amdgcn_s_barrier();
        asm volatile("" ::: "memory");

        int cur = 0;
        for (int kt = 0; kt < 25; ++kt){
            const unsigned short* kb = &k_lds[cur][0];
            const unsigned short* vb = &v_lds[cur][0];
            __builtin_amdgcn_s_setprio(1);
            short8 ka0 = *reinterpret_cast<const short8*>(kb + (size_t)( 0 + ql)*40 + lg*8);
            short8 ka1 = *reinterpret_cast<const short8*>(kb + (size_t)(16 + ql)*40 + lg*8);
            short8 ka2 = *reinterpret_cast<const short8*>(kb + (size_t)(32 + ql)*40 + lg*8);
            short8 ka3 = *reinterpret_cast<const short8*>(kb + (size_t)(48 + ql)*40 + lg*8);

            f32x4 z = (f32x4){0.f,0.f,0.f,0.f};
            f32x4 p0 = __builtin_amdgcn_mfma_f32_16x16x32_bf16(ka0, qf, z, 0,0,0);
            f32x4 p1 = __builtin_amdgcn_mfma_f32_16x16x32_bf16(ka1, qf, z, 0,0,0);
            f32x4 p2 = __builtin_amdgcn_mfma_f32_16x16x32_bf16(ka2, qf, z, 0,0,0);
            f32x4 p3 = __builtin_amdgcn_mfma_f32_16x16x32_bf16(ka3, qf, z, 0,0,0);

            #pragma unroll
            for (int r=0;r<4;r++){
                p0[r] = fexp2(p0[r]);
                p1[r] = fexp2(p1[r]);
                p2[r] = fexp2(p2[r]);
                p3[r] = fexp2(p3[r]);
            }
            Sp += ((p0[0]+p0[1])+(p0[2]+p0[3])) + ((p1[0]+p1[1])+(p1[2]+p1[3]))
                + ((p2[0]+p2[1])+(p2[2]+p2[3])) + ((p3[0]+p3[1])+(p3[2]+p3[3]));

            union { int4 i; short8 s8; } pb0, pb1;
            pb0.i = make_int4((int)cvtpk(p0[0],p0[1]), (int)cvtpk(p0[2],p0[3]),
                              (int)cvtpk(p1[0],p1[1]), (int)cvtpk(p1[2],p1[3]));
            pb1.i = make_int4((int)cvtpk(p2[0],p2[1]), (int)cvtpk(p2[2],p2[3]),
                              (int)cvtpk(p3[0],p3[1]), (int)cvtpk(p3[2],p3[3]));

            short8 va0 = *reinterpret_cast<const short8*>(vb +    0 + lane*8);
            short8 va1 = *reinterpret_cast<const short8*>(vb +  512 + lane*8);
            short8 va2 = *reinterpret_cast<const short8*>(vb + 1024 + lane*8);
            short8 va3 = *reinterpret_cast<const short8*>(vb + 1536 + lane*8);

            o0 = __builtin_amdgcn_mfma_f32_16x16x32_bf16(va0, pb0.s8, o0, 0,0,0);
            o0 = __builtin_amdgcn_mfma_f32_16x16x32_bf16(va1, pb1.s8, o0, 0,0,0);
            o1 = __builtin_amdgcn_mfma_f32_16x16x32_bf16(va2, pb0.s8, o1, 0,0,0);
            o1 = __builtin_amdgcn_mfma_f32_16x16x32_bf16(va3, pb1.s8, o1, 0,0,0);
            __builtin_amdgcn_s_setprio(0);

            asm volatile("" ::: "memory");
            __builtin_amdgcn_s_barrier();
            asm volatile("" ::: "memory");
            cur = (cur==2) ? 0 : cur+1;
        }

        Sp += __shfl_xor(Sp, 16);
        Sp += __shfl_xor(Sp, 32);
        float inv = 1.f / Sp;
        size_t rowoff = ((size_t)b*N_SPATIAL + nq)*256 + h*32;
        uint2 w0 = make_uint2((unsigned)pack2(o0[0]*inv, o0[1]*inv),
                              (unsigned)pack2(o0[2]*inv, o0[3]*inv));
        *reinterpret_cast<uint2*>(ao_t + rowoff + 4*lg) = w0;
        uint2 w1 = make_uint2((unsigned)pack2(o1[0]*inv, o1[1]*inv),
                              (unsigned)pack2(o1[2]*inv, o1[3]*inv));
        *reinterpret_cast<uint2*>(ao_t + rowoff + 16 + 4*lg) = w1;
    } else {
        int pi = tid & 255;
        const unsigned short* kg = ksrc + pi*8;
        const unsigned short* vg = vms  + pi*8;
        unsigned short* kd = &k_lds[0][0] + (pi>>2)*40 + (pi&3)*8;
        unsigned short* vd = &v_lds[0][0] + pi*8;

        int4 a0 = *reinterpret_cast<const int4*>(kg);
        int4 b0 = *reinterpret_cast<const int4*>(vg);
        *reinterpret_cast<int4*>(kd) = a0;
        *reinterpret_cast<int4*>(vd) = b0;
        int4 a1 = *reinterpret_cast<const int4*>(kg + 2048);
        int4 b1 = *reinterpret_cast<const int4*>(vg + 2048);
        *reinterpret_cast<int4*>(kd + 2560) = a1;
        *reinterpret_cast<int4*>(vd + 2048) = b1;
        int4 hk = *reinterpret_cast<const int4*>(kg + 4096);
        int4 hv = *reinterpret_cast<const int4*>(vg + 4096);
        asm volatile("s_waitcnt lgkmcnt(0)" ::: "memory");
        __builtin_amdgcn_s_barrier();
        asm volatile("" ::: "memory");

        int wb = 2;
        for (int kt = 0; kt < 25; ++kt){
            if (kt < 23){
                *reinterpret_cast<int4*>(kd + wb*2560) = hk;
                *reinterpret_cast<int4*>(vd + wb*2048) = hv;
            }
            if (kt < 22){
                hk = *reinterpret_cast<const int4*>(kg + (size_t)(kt+3)*2048);
                hv = *reinterpret_cast<const int4*>(vg + (size_t)(kt+3)*2048);
            }
            asm volatile("s_waitcnt lgkmcnt(0)" ::: "memory");
            __builtin_amdgcn_s_barrier();
            asm volatile("" ::: "memory");
            wb = (wb==2) ? 0 : wb+1;
        }
    }
}

// ---------------- K3: proj GEMM, 64o x 32n tiles (800 blocks), padded LDS ----------------
__global__ __launch_bounds__(256) void k_proj4(const unsigned short* __restrict__ ao_t,
                                               const float* __restrict__ wp,
                                               const float* __restrict__ g,
                                               const float* __restrict__ be,
                                               const float* __restrict__ mu,
                                               const float* __restrict__ va,
                                               float* __restrict__ out){
    __shared__ alignas(16) unsigned short a_lds[64*LSTR];
    __shared__ alignas(16) unsigned short b_lds[32*LSTR];
    int bi = blockIdx.x;                      // 800 = 4b * 4ot * 50nt
    int b = bi / 200, ot = (bi/50) % 4, nt = bi % 50;
    int o0 = ot*64, n0 = nt*32;
    int tid = threadIdx.x, w = tid>>6, lane = tid&63;
    int arow = tid>>2, acol8 = (tid&3)*8;
    int brow = tid>>3, bcol4 = (tid&7)*4;
    int ql = lane&15, lg = lane>>4;
    f32x4 acc[2];
    acc[0] = (f32x4){0.f,0.f,0.f,0.f};
    acc[1] = (f32x4){0.f,0.f,0.f,0.f};
    const float* asrc = wp + (size_t)(o0+arow)*256 + acol8;
    const unsigned short* bsrc = ao_t + ((size_t)b*N_SPATIAL + n0 + brow)*256 + bcol4;
    for (int k0=0; k0<256; k0+=32){
        float4 f0 = *reinterpret_cast<const float4*>(asrc + k0);
        float4 f1 = *reinterpret_cast<const float4*>(asrc + k0 + 4);
        int4 av; av.x = pack2(f0.x,f0.y); av.y = pack2(f0.z,f0.w);
                 av.z = pack2(f1.x,f1.y); av.w = pack2(f1.z,f1.w);
        *reinterpret_cast<int4*>(&a_lds[arow*LSTR + acol8]) = av;
        *reinterpret_cast<uint2*>(&b_lds[brow*LSTR + bcol4]) = *reinterpret_cast<const uint2*>(bsrc + k0);
        __syncthreads();
        short8 af = *reinterpret_cast<const short8*>(&a_lds[(16*w + ql)*LSTR + lg*8]);
        #pragma unroll
        for (int t=0;t<2;t++){
            short8 bf = *reinterpret_cast<const short8*>(&b_lds[(16*t + ql)*LSTR + lg*8]);
            acc[t] = __builtin_amdgcn_mfma_f32_16x16x32_bf16(af, bf, acc[t], 0, 0, 0);
        }
        __syncthreads();
    }
    #pragma unroll
    for (int r=0;r<4;r++){
        int o = o0 + 16*w + lg*4 + r;
        float inv = g[o] * rsqrtf(va[o] + 1e-5f);
        float b2  = be[o] - mu[o]*inv;
        float* dst = out + ((size_t)(b*256 + o))*N_SPATIAL;
        #pragma unroll
        for (int t=0;t<2;t++){
            int n = n0 + 16*t + ql;
            float z = acc[t][r]*inv + b2;
            float y = z / (1.f + __expf(-z));
            dst[n] = y;
        }
    }
}

extern "C" void kernel_launch(void* const* d_in, const int* in_sizes, int n_in,
                              void* d_out, int out_size, void* d_ws, size_t ws_size,
                              hipStream_t stream) {
    const float* x      = (const float*)d_in[0];
    const float* qkv_w  = (const float*)d_in[1];
    const float* qkv_g  = (const float*)d_in[2];
    const float* qkv_b  = (const float*)d_in[3];
    const float* qkv_m  = (const float*)d_in[4];
    const float* qkv_v  = (const float*)d_in[5];
    const float* proj_w = (const float*)d_in[6];
    const float* proj_g = (const float*)d_in[7];
    const float* proj_b = (const float*)d_in[8];
    const float* proj_m = (const float*)d_in[9];
    const float* proj_v = (const float*)d_in[10];
    const float* pe_w   = (const float*)d_in[11];
    const float* pe_g   = (const float*)d_in[12];
    const float* pe_b   = (const float*)d_in[13];
    const float* pe_m   = (const float*)d_in[14];
    const float* pe_v   = (const float*)d_in[15];

    char* ws = (char*)d_ws;
    unsigned short* v_mf = (unsigned short*)(ws);                 // 3,276,800
    unsigned short* qk_t = (unsigned short*)(ws + 3276800);       // 6,553,600
    unsigned short* ao_t = (unsigned short*)(ws + 9830400);       // 3,276,800
    float* outp = (float*)d_out;

    k_fuse <<<1632,256, 0, stream>>>(x, qkv_w, qkv_g, qkv_b, qkv_m, qkv_v,
                                     pe_w, pe_g, pe_b, pe_m, pe_v, qk_t, v_mf);
    k_attn7<<<800, 512, 0, stream>>>(qk_t, v_mf, ao_t);
    k_proj4<<<800, 256, 0, stream>>>(ao_t, proj_w, proj_g, proj_b, proj_m, proj_v, outp);
}

// Round 24
// 50.886 us; speedup vs baseline: 1.1326x; 1.0250x over previous
//
#include <hip/hip_runtime.h>
#include <hip/hip_bf16.h>

typedef __attribute__((ext_vector_type(8))) short short8;
typedef __attribute__((ext_vector_type(4))) float f32x4;

__device__ __forceinline__ unsigned short f2bf(float f){
    union { float f; unsigned u; } uf; uf.f = f;
    unsigned u = uf.u;
    u += 0x7FFFu + ((u >> 16) & 1u);   // RNE
    return (unsigned short)(u >> 16);
}
__device__ __forceinline__ int pack2(float a, float b){
    union { float f; unsigned u; } ua, ub; ua.f = a; ub.f = b;
    unsigned x = ua.u; x += 0x7FFFu + ((x >> 16) & 1u);
    unsigned y = ub.u; y += 0x7FFFu + ((y >> 16) & 1u);
    return (int)((x >> 16) | (y & 0xFFFF0000u));
}
__device__ __forceinline__ unsigned cvtpk(float lo, float hi){
    unsigned r;
    asm("v_cvt_pk_bf16_f32 %0, %1, %2" : "=v"(r) : "v"(lo), "v"(hi));
    return r;
}
__device__ __forceinline__ float fexp2(float x){
    return __builtin_amdgcn_exp2f(x);   // v_exp_f32: 2^x
}

#define N_SPATIAL 1600
#define QSCALE_LOG2E 0.25506601f   /* 32^-0.5 * log2(e), folded into q */
#define LSTR 40                    /* padded LDS row stride (u16) for GEMM tiles */

// ---------------- K1 fused: [0,832) qkv GEMM (XCD-grouped by (b,nt)) ; [832,1632) pev (XCD-grouped by (b,h)) ----------------
__global__ __launch_bounds__(256) void k_fuse(const float* __restrict__ x,
                                              const float* __restrict__ wq,
                                              const float* __restrict__ qg,
                                              const float* __restrict__ qb,
                                              const float* __restrict__ qm,
                                              const float* __restrict__ qv,
                                              const float* __restrict__ pw,
                                              const float* __restrict__ pg,
                                              const float* __restrict__ pb,
                                              const float* __restrict__ pm,
                                              const float* __restrict__ pv,
                                              unsigned short* __restrict__ qk_t,
                                              unsigned short* __restrict__ v_mf){
    __shared__ alignas(16) char smem[20864];
    int blk = blockIdx.x;
    int tid = threadIdx.x;
    if (blk < 832){
        // ---------------- qkv GEMM ----------------
        // XCD swizzle: the 8 ot-blocks of one (b,nt) share blockIdx%8 -> one XCD L2
        int low3 = blk & 7, inner = blk >> 3;
        int ot = inner & 7, ghi = inner >> 3;
        int g = ghi*8 + low3;
        if (g >= 100) return;            // 32 dead slots
        int b = g/25, nt = g%25;
        int o0 = ot*64, n0 = nt*64;

        unsigned short* a_lds = (unsigned short*)smem;           // 64*LSTR
        unsigned short* b_lds = a_lds + 64*LSTR;                 // 64*LSTR
        int w = tid>>6, lane = tid&63;
        int row = tid>>2, col8 = (tid&3)*8;
        int bn = tid & 63, bc0 = (tid>>6)*8;
        int ql = lane&15, lg = lane>>4;
        f32x4 acc[4];
        #pragma unroll
        for (int t=0;t<4;t++) acc[t] = (f32x4){0.f,0.f,0.f,0.f};
        const float* asrc = wq + (size_t)(o0+row)*256 + col8;
        const float* xb = x + (size_t)b*256*N_SPATIAL + n0 + bn;
        for (int k0=0; k0<256; k0+=32){
            float4 f0 = *reinterpret_cast<const float4*>(asrc + k0);
            float4 f1 = *reinterpret_cast<const float4*>(asrc + k0 + 4);
            int4 av; av.x = pack2(f0.x,f0.y); av.y = pack2(f0.z,f0.w);
                     av.z = pack2(f1.x,f1.y); av.w = pack2(f1.z,f1.w);
            *reinterpret_cast<int4*>(&a_lds[row*LSTR + col8]) = av;
            float v0 = xb[(size_t)(k0+bc0+0)*N_SPATIAL];
            float v1 = xb[(size_t)(k0+bc0+1)*N_SPATIAL];
            float v2 = xb[(size_t)(k0+bc0+2)*N_SPATIAL];
            float v3 = xb[(size_t)(k0+bc0+3)*N_SPATIAL];
            float v4 = xb[(size_t)(k0+bc0+4)*N_SPATIAL];
            float v5 = xb[(size_t)(k0+bc0+5)*N_SPATIAL];
            float v6 = xb[(size_t)(k0+bc0+6)*N_SPATIAL];
            float v7 = xb[(size_t)(k0+bc0+7)*N_SPATIAL];
            int4 bv; bv.x = pack2(v0,v1); bv.y = pack2(v2,v3);
                     bv.z = pack2(v4,v5); bv.w = pack2(v6,v7);
            *reinterpret_cast<int4*>(&b_lds[bn*LSTR + bc0]) = bv;
            __syncthreads();
            __builtin_amdgcn_s_setprio(1);
            short8 af = *reinterpret_cast<const short8*>(&a_lds[(16*w + ql)*LSTR + lg*8]);
            #pragma unroll
            for (int t=0;t<4;t++){
                short8 bf = *reinterpret_cast<const short8*>(&b_lds[(16*t + ql)*LSTR + lg*8]);
                acc[t] = __builtin_amdgcn_mfma_f32_16x16x32_bf16(af, bf, acc[t], 0, 0, 0);
            }
            __builtin_amdgcn_s_setprio(0);
            __syncthreads();
        }
        int ob = o0 + 16*w + 4*lg;
        int grp = ob >> 5, d0 = ob & 31;
        float invr[4], b2r[4];
        #pragma unroll
        for (int r=0;r<4;r++){
            int o = ob + r;
            invr[r] = qg[o] * rsqrtf(qv[o] + 1e-5f);
            b2r[r]  = qb[o] - qm[o]*invr[r];
        }
        float qs = (ob < 256) ? QSCALE_LOG2E : 1.0f;
        unsigned short* dstb = qk_t + ((size_t)(b*16 + grp)*N_SPATIAL)*32 + d0;
        #pragma unroll
        for (int t=0;t<4;t++){
            int n = n0 + 16*t + ql;
            float y[4];
            #pragma unroll
            for (int r=0;r<4;r++){
                float z = acc[t][r]*invr[r] + b2r[r];
                y[r] = (z / (1.f + __expf(-z))) * qs;
            }
            uint2 wv = make_uint2((unsigned)pack2(y[0],y[1]), (unsigned)pack2(y[2],y[3]));
            *reinterpret_cast<uint2*>(dstb + (size_t)n*32) = wv;
        }
        return;
    }
    // ---------------- pev ----------------
    {
        // XCD swizzle: the 25 kt-blocks of one (b,h) share blockIdx%8 -> one XCD L2
        int pl = blk - 832;               // [0,800)
        int low3 = pl & 7, inner = pl >> 3;
        int kt = inner % 25, gph = (inner/25)*8 + low3;
        int b = gph >> 3, h = gph & 7;
        int pbi = b*200 + h*25 + kt;      // original output index

        float (*xs)[163] = reinterpret_cast<float(*)[163]>(smem);
        int winStart = kt*64 - 48;
        const float* xbase = x + ((size_t)(b*256 + h*32))*N_SPATIAL;
        #pragma unroll
        for (int i=0;i<20;i++){
            int idx = tid + i*256;
            int row = idx / 160, col = idx - row*160;
            int n = winStart + col;
            float val = ((unsigned)n < 1600u) ? xbase[(size_t)row*N_SPATIAL + n] : 0.f;
            xs[row][col] = val;
        }
        __syncthreads();

        int f = tid>>6, lane = tid&63, ql = lane&15, lg = lane>>4;
        int d = (f>>1)*16 + ql;
        int c = h*32 + d;
        float inv = pg[c]*rsqrtf(pv[c]+1e-5f);
        float bias = pb[c]-pm[c]*inv;
        const float* w9 = pw + c*9;
        float w00=w9[0],w01=w9[1],w02=w9[2],w10=w9[3],w11=w9[4],w12=w9[5],w20=w9[6],w21=w9[7],w22=w9[8];
        const float* xr = xs[d];
        union { unsigned short u[8]; int4 i4; } vals;
        #pragma unroll
        for (int j=0;j<8;j++){
            int key = (f&1)*32 + (j>>2)*16 + 4*lg + (j&3);
            int n = kt*64 + key;
            int hh = n/40, ww = n - hh*40;
            int col = key + 48;
            float acc = 0.f;
            if (hh > 0){
                if (ww > 0)  acc += xr[col-41]*w00;
                             acc += xr[col-40]*w01;
                if (ww < 39) acc += xr[col-39]*w02;
            }
            if (ww > 0)  acc += xr[col-1]*w10;
                         acc += xr[col]*w11;
            if (ww < 39) acc += xr[col+1]*w12;
            if (hh < 39){
                if (ww > 0)  acc += xr[col+39]*w20;
                             acc += xr[col+40]*w21;
                if (ww < 39) acc += xr[col+41]*w22;
            }
            float out = xr[col] + acc*inv + bias;
            vals.u[j] = f2bf(out);
        }
        *reinterpret_cast<int4*>(v_mf + ((size_t)(pbi*4 + f)*64 + lane)*8) = vals.i4;
    }
}

// ---------------- K2: attention v7 + XCD swizzle + T5 setprio (r23 exact) ----------------
__global__ __launch_bounds__(512) void k_attn7(const unsigned short* __restrict__ qk_t,
                                               const unsigned short* __restrict__ v_mf,
                                               unsigned short* __restrict__ ao_t){
    __shared__ alignas(16) unsigned short k_lds[3][64*40];
    __shared__ alignas(16) unsigned short v_lds[3][2048];
    int l = blockIdx.x;
    int xc = l & 7, j = l >> 3;
    int gg = xc + 8*(j/25);
    int bi = 25*gg + (j%25);
    int b = gg >> 3, h = gg & 7, qt = bi % 25;
    int tid = threadIdx.x, w = tid>>6, lane = tid&63;

    const unsigned short* ksrc = qk_t + ((size_t)(b*16+8+h)*N_SPATIAL)*32;
    const unsigned short* vms  = v_mf + (size_t)(b*200 + h*25)*2048;

    if (w < 4){
        int ql = lane&15, lg = lane>>4;
        int nq = qt*64 + w*16 + ql;
        const unsigned short* qsrc = qk_t + ((size_t)(b*16+h)*N_SPATIAL)*32;
        short8 qf = *reinterpret_cast<const short8*>(qsrc + (size_t)nq*32 + lg*8);
        f32x4 o0 = (f32x4){0.f,0.f,0.f,0.f};
        f32x4 o1 = (f32x4){0.f,0.f,0.f,0.f};
        float Sp = 0.f;

        asm volatile("" ::: "memory");
        __builtin_amdgcn_s_barrier();
        asm volatile("" ::: "memory");

        int cur = 0;
        for (int kt = 0; kt < 25; ++kt){
            const unsigned short* kb = &k_lds[cur][0];
            const unsigned short* vb = &v_lds[cur][0];
            __builtin_amdgcn_s_setprio(1);
            short8 ka0 = *reinterpret_cast<const short8*>(kb + (size_t)( 0 + ql)*40 + lg*8);
            short8 ka1 = *reinterpret_cast<const short8*>(kb + (size_t)(16 + ql)*40 + lg*8);
            short8 ka2 = *reinterpret_cast<const short8*>(kb + (size_t)(32 + ql)*40 + lg*8);
            short8 ka3 = *reinterpret_cast<const short8*>(kb + (size_t)(48 + ql)*40 + lg*8);

            f32x4 z = (f32x4){0.f,0.f,0.f,0.f};
            f32x4 p0 = __builtin_amdgcn_mfma_f32_16x16x32_bf16(ka0, qf, z, 0,0,0);
            f32x4 p1 = __builtin_amdgcn_mfma_f32_16x16x32_bf16(ka1, qf, z, 0,0,0);
            f32x4 p2 = __builtin_amdgcn_mfma_f32_16x16x32_bf16(ka2, qf, z, 0,0,0);
            f32x4 p3 = __builtin_amdgcn_mfma_f32_16x16x32_bf16(ka3, qf, z, 0,0,0);

            #pragma unroll
            for (int r=0;r<4;r++){
                p0[r] = fexp2(p0[r]);
                p1[r] = fexp2(p1[r]);
                p2[r] = fexp2(p2[r]);
                p3[r] = fexp2(p3[r]);
            }
            Sp += ((p0[0]+p0[1])+(p0[2]+p0[3])) + ((p1[0]+p1[1])+(p1[2]+p1[3]))
                + ((p2[0]+p2[1])+(p2[2]+p2[3])) + ((p3[0]+p3[1])+(p3[2]+p3[3]));

            union { int4 i; short8 s8; } pb0, pb1;
            pb0.i = make_int4((int)cvtpk(p0[0],p0[1]), (int)cvtpk(p0[2],p0[3]),
                              (int)cvtpk(p1[0],p1[1]), (int)cvtpk(p1[2],p1[3]));
            pb1.i = make_int4((int)cvtpk(p2[0],p2[1]), (int)cvtpk(p2[2],p2[3]),
                              (int)cvtpk(p3[0],p3[1]), (int)cvtpk(p3[2],p3[3]));

            short8 va0 = *reinterpret_cast<const short8*>(vb +    0 + lane*8);
            short8 va1 = *reinterpret_cast<const short8*>(vb +  512 + lane*8);
            short8 va2 = *reinterpret_cast<const short8*>(vb + 1024 + lane*8);
            short8 va3 = *reinterpret_cast<const short8*>(vb + 1536 + lane*8);

            o0 = __builtin_amdgcn_mfma_f32_16x16x32_bf16(va0, pb0.s8, o0, 0,0,0);
            o0 = __builtin_amdgcn_mfma_f32_16x16x32_bf16(va1, pb1.s8, o0, 0,0,0);
            o1 = __builtin_amdgcn_mfma_f32_16x16x32_bf16(va2, pb0.s8, o1, 0,0,0);
            o1 = __builtin_amdgcn_mfma_f32_16x16x32_bf16(va3, pb1.s8, o1, 0,0,0);
            __builtin_amdgcn_s_setprio(0);

            asm volatile("" ::: "memory");
            __builtin_amdgcn_s_barrier();
            asm volatile("" ::: "memory");
            cur = (cur==2) ? 0 : cur+1;
        }

        Sp += __shfl_xor(Sp, 16);
        Sp += __shfl_xor(Sp, 32);
        float inv = 1.f / Sp;
        size_t rowoff = ((size_t)b*N_SPATIAL + nq)*256 + h*32;
        uint2 w0 = make_uint2((unsigned)pack2(o0[0]*inv, o0[1]*inv),
                              (unsigned)pack2(o0[2]*inv, o0[3]*inv));
        *reinterpret_cast<uint2*>(ao_t + rowoff + 4*lg) = w0;
        uint2 w1 = make_uint2((unsigned)pack2(o1[0]*inv, o1[1]*inv),
                              (unsigned)pack2(o1[2]*inv, o1[3]*inv));
        *reinterpret_cast<uint2*>(ao_t + rowoff + 16 + 4*lg) = w1;
    } else {
        int pi = tid & 255;
        const unsigned short* kg = ksrc + pi*8;
        const unsigned short* vg = vms  + pi*8;
        unsigned short* kd = &k_lds[0][0] + (pi>>2)*40 + (pi&3)*8;
        unsigned short* vd = &v_lds[0][0] + pi*8;

        int4 a0 = *reinterpret_cast<const int4*>(kg);
        int4 b0 = *reinterpret_cast<const int4*>(vg);
        *reinterpret_cast<int4*>(kd) = a0;
        *reinterpret_cast<int4*>(vd) = b0;
        int4 a1 = *reinterpret_cast<const int4*>(kg + 2048);
        int4 b1 = *reinterpret_cast<const int4*>(vg + 2048);
        *reinterpret_cast<int4*>(kd + 2560) = a1;
        *reinterpret_cast<int4*>(vd + 2048) = b1;
        int4 hk = *reinterpret_cast<const int4*>(kg + 4096);
        int4 hv = *reinterpret_cast<const int4*>(vg + 4096);
        asm volatile("s_waitcnt lgkmcnt(0)" ::: "memory");
        __builtin_amdgcn_s_barrier();
        asm volatile("" ::: "memory");

        int wb = 2;
        for (int kt = 0; kt < 25; ++kt){
            if (kt < 23){
                *reinterpret_cast<int4*>(kd + wb*2560) = hk;
                *reinterpret_cast<int4*>(vd + wb*2048) = hv;
            }
            if (kt < 22){
                hk = *reinterpret_cast<const int4*>(kg + (size_t)(kt+3)*2048);
                hv = *reinterpret_cast<const int4*>(vg + (size_t)(kt+3)*2048);
            }
            asm volatile("s_waitcnt lgkmcnt(0)" ::: "memory");
            __builtin_amdgcn_s_barrier();
            asm volatile("" ::: "memory");
            wb = (wb==2) ? 0 : wb+1;
        }
    }
}

// ---------------- K3: proj GEMM, 64o x 32n tiles, XCD-grouped by (b,nt) ----------------
__global__ __launch_bounds__(256) void k_proj4(const unsigned short* __restrict__ ao_t,
                                               const float* __restrict__ wp,
                                               const float* __restrict__ g,
                                               const float* __restrict__ be,
                                               const float* __restrict__ mu,
                                               const float* __restrict__ va,
                                               float* __restrict__ out){
    __shared__ alignas(16) unsigned short a_lds[64*LSTR];
    __shared__ alignas(16) unsigned short b_lds[32*LSTR];
    // XCD swizzle: the 4 ot-blocks of one (b,nt) share blockIdx%8 -> one XCD L2
    int l = blockIdx.x;                       // 800 = 8 * (4ot * 25ghi)
    int low3 = l & 7, inner = l >> 3;
    int ot = inner & 3, ghi = inner >> 2;     // ghi in [0,25)
    int gidx = ghi*8 + low3;                  // [0,200) = b*50 + nt
    int b = gidx/50, nt = gidx%50;
    int o0 = ot*64, n0 = nt*32;
    int tid = threadIdx.x, w = tid>>6, lane = tid&63;
    int arow = tid>>2, acol8 = (tid&3)*8;
    int brow = tid>>3, bcol4 = (tid&7)*4;
    int ql = lane&15, lg = lane>>4;
    f32x4 acc[2];
    acc[0] = (f32x4){0.f,0.f,0.f,0.f};
    acc[1] = (f32x4){0.f,0.f,0.f,0.f};
    const float* asrc = wp + (size_t)(o0+arow)*256 + acol8;
    const unsigned short* bsrc = ao_t + ((size_t)b*N_SPATIAL + n0 + brow)*256 + bcol4;
    for (int k0=0; k0<256; k0+=32){
        float4 f0 = *reinterpret_cast<const float4*>(asrc + k0);
        float4 f1 = *reinterpret_cast<const float4*>(asrc + k0 + 4);
        int4 av; av.x = pack2(f0.x,f0.y); av.y = pack2(f0.z,f0.w);
                 av.z = pack2(f1.x,f1.y); av.w = pack2(f1.z,f1.w);
        *reinterpret_cast<int4*>(&a_lds[arow*LSTR + acol8]) = av;
        *reinterpret_cast<uint2*>(&b_lds[brow*LSTR + bcol4]) = *reinterpret_cast<const uint2*>(bsrc + k0);
        __syncthreads();
        short8 af = *reinterpret_cast<const short8*>(&a_lds[(16*w + ql)*LSTR + lg*8]);
        #pragma unroll
        for (int t=0;t<2;t++){
            short8 bf = *reinterpret_cast<const short8*>(&b_lds[(16*t + ql)*LSTR + lg*8]);
            acc[t] = __builtin_amdgcn_mfma_f32_16x16x32_bf16(af, bf, acc[t], 0, 0, 0);
        }
        __syncthreads();
    }
    #pragma unroll
    for (int r=0;r<4;r++){
        int o = o0 + 16*w + lg*4 + r;
        float inv = g[o] * rsqrtf(va[o] + 1e-5f);
        float b2  = be[o] - mu[o]*inv;
        float* dst = out + ((size_t)(b*256 + o))*N_SPATIAL;
        #pragma unroll
        for (int t=0;t<2;t++){
            int n = n0 + 16*t + ql;
            float z = acc[t][r]*inv + b2;
            float y = z / (1.f + __expf(-z));
            dst[n] = y;
        }
    }
}

extern "C" void kernel_launch(void* const* d_in, const int* in_sizes, int n_in,
                              void* d_out, int out_size, void* d_ws, size_t ws_size,
                              hipStream_t stream) {
    const float* x      = (const float*)d_in[0];
    const float* qkv_w  = (const float*)d_in[1];
    const float* qkv_g  = (const float*)d_in[2];
    const float* qkv_b  = (const float*)d_in[3];
    const float* qkv_m  = (const float*)d_in[4];
    const float* qkv_v  = (const float*)d_in[5];
    const float* proj_w = (const float*)d_in[6];
    const float* proj_g = (const float*)d_in[7];
    const float* proj_b = (const float*)d_in[8];
    const float* proj_m = (const float*)d_in[9];
    const float* proj_v = (const float*)d_in[10];
    const float* pe_w   = (const float*)d_in[11];
    const float* pe_g   = (const float*)d_in[12];
    const float* pe_b   = (const float*)d_in[13];
    const float* pe_m   = (const float*)d_in[14];
    const float* pe_v   = (const float*)d_in[15];

    char* ws = (char*)d_ws;
    unsigned short* v_mf = (unsigned short*)(ws);                 // 3,276,800
    unsigned short* qk_t = (unsigned short*)(ws + 3276800);       // 6,553,600
    unsigned short* ao_t = (unsigned short*)(ws + 9830400);       // 3,276,800
    float* outp = (float*)d_out;

    k_fuse <<<1632,256, 0, stream>>>(x, qkv_w, qkv_g, qkv_b, qkv_m, qkv_v,
                                     pe_w, pe_g, pe_b, pe_m, pe_v, qk_t, v_mf);
    k_attn7<<<800, 512, 0, stream>>>(qk_t, v_mf, ao_t);
    k_proj4<<<800, 256, 0, stream>>>(ao_t, proj_w, proj_g, proj_b, proj_m, proj_v, outp);
}

// Round 25
// 50.504 us; speedup vs baseline: 1.1412x; 1.0076x over previous
//
#include <hip/hip_runtime.h>
#include <hip/hip_bf16.h>

typedef __attribute__((ext_vector_type(8))) short short8;
typedef __attribute__((ext_vector_type(4))) float f32x4;

__device__ __forceinline__ unsigned short f2bf(float f){
    union { float f; unsigned u; } uf; uf.f = f;
    unsigned u = uf.u;
    u += 0x7FFFu + ((u >> 16) & 1u);   // RNE
    return (unsigned short)(u >> 16);
}
__device__ __forceinline__ int pack2(float a, float b){
    union { float f; unsigned u; } ua, ub; ua.f = a; ub.f = b;
    unsigned x = ua.u; x += 0x7FFFu + ((x >> 16) & 1u);
    unsigned y = ub.u; y += 0x7FFFu + ((y >> 16) & 1u);
    return (int)((x >> 16) | (y & 0xFFFF0000u));
}
__device__ __forceinline__ unsigned cvtpk(float lo, float hi){
    unsigned r;
    asm("v_cvt_pk_bf16_f32 %0, %1, %2" : "=v"(r) : "v"(lo), "v"(hi));
    return r;
}
__device__ __forceinline__ float fexp2(float x){
    return __builtin_amdgcn_exp2f(x);   // v_exp_f32: 2^x
}

#define N_SPATIAL 1600
#define QSCALE_LOG2E 0.25506601f   /* 32^-0.5 * log2(e), folded into q */
#define LSTR 40                    /* padded LDS row stride (u16) for GEMM tiles */

// ---------------- K1 fused: [0,832) qkv GEMM (XCD-grouped by (b,nt)) ; [832,1632) pev (XCD-grouped by (b,h)) ----------------
__global__ __launch_bounds__(256) void k_fuse(const float* __restrict__ x,
                                              const float* __restrict__ wq,
                                              const float* __restrict__ qg,
                                              const float* __restrict__ qb,
                                              const float* __restrict__ qm,
                                              const float* __restrict__ qv,
                                              const float* __restrict__ pw,
                                              const float* __restrict__ pg,
                                              const float* __restrict__ pb,
                                              const float* __restrict__ pm,
                                              const float* __restrict__ pv,
                                              unsigned short* __restrict__ qk_t,
                                              unsigned short* __restrict__ v_mf){
    __shared__ alignas(16) char smem[20864];
    int blk = blockIdx.x;
    int tid = threadIdx.x;
    if (blk < 832){
        // ---------------- qkv GEMM ----------------
        int low3 = blk & 7, inner = blk >> 3;
        int ot = inner & 7, ghi = inner >> 3;
        int g = ghi*8 + low3;
        if (g >= 100) return;            // 32 dead slots
        int b = g/25, nt = g%25;
        int o0 = ot*64, n0 = nt*64;

        unsigned short* a_lds = (unsigned short*)smem;           // 64*LSTR
        unsigned short* b_lds = a_lds + 64*LSTR;                 // 64*LSTR
        int w = tid>>6, lane = tid&63;
        int row = tid>>2, col8 = (tid&3)*8;
        int bn = tid & 63, bc0 = (tid>>6)*8;
        int ql = lane&15, lg = lane>>4;
        f32x4 acc[4];
        #pragma unroll
        for (int t=0;t<4;t++) acc[t] = (f32x4){0.f,0.f,0.f,0.f};
        const float* asrc = wq + (size_t)(o0+row)*256 + col8;
        const float* xb = x + (size_t)b*256*N_SPATIAL + n0 + bn;
        for (int k0=0; k0<256; k0+=32){
            float4 f0 = *reinterpret_cast<const float4*>(asrc + k0);
            float4 f1 = *reinterpret_cast<const float4*>(asrc + k0 + 4);
            int4 av; av.x = pack2(f0.x,f0.y); av.y = pack2(f0.z,f0.w);
                     av.z = pack2(f1.x,f1.y); av.w = pack2(f1.z,f1.w);
            *reinterpret_cast<int4*>(&a_lds[row*LSTR + col8]) = av;
            float v0 = xb[(size_t)(k0+bc0+0)*N_SPATIAL];
            float v1 = xb[(size_t)(k0+bc0+1)*N_SPATIAL];
            float v2 = xb[(size_t)(k0+bc0+2)*N_SPATIAL];
            float v3 = xb[(size_t)(k0+bc0+3)*N_SPATIAL];
            float v4 = xb[(size_t)(k0+bc0+4)*N_SPATIAL];
            float v5 = xb[(size_t)(k0+bc0+5)*N_SPATIAL];
            float v6 = xb[(size_t)(k0+bc0+6)*N_SPATIAL];
            float v7 = xb[(size_t)(k0+bc0+7)*N_SPATIAL];
            int4 bv; bv.x = pack2(v0,v1); bv.y = pack2(v2,v3);
                     bv.z = pack2(v4,v5); bv.w = pack2(v6,v7);
            *reinterpret_cast<int4*>(&b_lds[bn*LSTR + bc0]) = bv;
            __syncthreads();
            __builtin_amdgcn_s_setprio(1);
            short8 af = *reinterpret_cast<const short8*>(&a_lds[(16*w + ql)*LSTR + lg*8]);
            #pragma unroll
            for (int t=0;t<4;t++){
                short8 bf = *reinterpret_cast<const short8*>(&b_lds[(16*t + ql)*LSTR + lg*8]);
                acc[t] = __builtin_amdgcn_mfma_f32_16x16x32_bf16(af, bf, acc[t], 0, 0, 0);
            }
            __builtin_amdgcn_s_setprio(0);
            __syncthreads();
        }
        int ob = o0 + 16*w + 4*lg;
        int grp = ob >> 5, d0 = ob & 31;
        float invr[4], b2r[4];
        #pragma unroll
        for (int r=0;r<4;r++){
            int o = ob + r;
            invr[r] = qg[o] * rsqrtf(qv[o] + 1e-5f);
            b2r[r]  = qb[o] - qm[o]*invr[r];
        }
        float qs = (ob < 256) ? QSCALE_LOG2E : 1.0f;
        unsigned short* dstb = qk_t + ((size_t)(b*16 + grp)*N_SPATIAL)*32 + d0;
        #pragma unroll
        for (int t=0;t<4;t++){
            int n = n0 + 16*t + ql;
            float y[4];
            #pragma unroll
            for (int r=0;r<4;r++){
                float z = acc[t][r]*invr[r] + b2r[r];
                y[r] = (z / (1.f + __expf(-z))) * qs;
            }
            uint2 wv = make_uint2((unsigned)pack2(y[0],y[1]), (unsigned)pack2(y[2],y[3]));
            *reinterpret_cast<uint2*>(dstb + (size_t)n*32) = wv;
        }
        return;
    }
    // ---------------- pev ----------------
    {
        int pl = blk - 832;               // [0,800)
        int low3 = pl & 7, inner = pl >> 3;
        int kt = inner % 25, gph = (inner/25)*8 + low3;
        int b = gph >> 3, h = gph & 7;
        int pbi = b*200 + h*25 + kt;      // original output index

        float (*xs)[163] = reinterpret_cast<float(*)[163]>(smem);
        int winStart = kt*64 - 48;
        const float* xbase = x + ((size_t)(b*256 + h*32))*N_SPATIAL;
        #pragma unroll
        for (int i=0;i<20;i++){
            int idx = tid + i*256;
            int row = idx / 160, col = idx - row*160;
            int n = winStart + col;
            float val = ((unsigned)n < 1600u) ? xbase[(size_t)row*N_SPATIAL + n] : 0.f;
            xs[row][col] = val;
        }
        __syncthreads();

        int f = tid>>6, lane = tid&63, ql = lane&15, lg = lane>>4;
        int d = (f>>1)*16 + ql;
        int c = h*32 + d;
        float inv = pg[c]*rsqrtf(pv[c]+1e-5f);
        float bias = pb[c]-pm[c]*inv;
        const float* w9 = pw + c*9;
        float w00=w9[0],w01=w9[1],w02=w9[2],w10=w9[3],w11=w9[4],w12=w9[5],w20=w9[6],w21=w9[7],w22=w9[8];
        const float* xr = xs[d];
        union { unsigned short u[8]; int4 i4; } vals;
        #pragma unroll
        for (int j=0;j<8;j++){
            int key = (f&1)*32 + (j>>2)*16 + 4*lg + (j&3);
            int n = kt*64 + key;
            int hh = n/40, ww = n - hh*40;
            int col = key + 48;
            float acc = 0.f;
            if (hh > 0){
                if (ww > 0)  acc += xr[col-41]*w00;
                             acc += xr[col-40]*w01;
                if (ww < 39) acc += xr[col-39]*w02;
            }
            if (ww > 0)  acc += xr[col-1]*w10;
                         acc += xr[col]*w11;
            if (ww < 39) acc += xr[col+1]*w12;
            if (hh < 39){
                if (ww > 0)  acc += xr[col+39]*w20;
                             acc += xr[col+40]*w21;
                if (ww < 39) acc += xr[col+41]*w22;
            }
            float out = xr[col] + acc*inv + bias;
            vals.u[j] = f2bf(out);
        }
        *reinterpret_cast<int4*>(v_mf + ((size_t)(pbi*4 + f)*64 + lane)*8) = vals.i4;
    }
}

// ---------------- K2: attention v7b — 4 consumer + 2 producer waves (384 thr, 5 blocks/CU) ----------------
__global__ __launch_bounds__(384) void k_attn7(const unsigned short* __restrict__ qk_t,
                                               const unsigned short* __restrict__ v_mf,
                                               unsigned short* __restrict__ ao_t){
    __shared__ alignas(16) unsigned short k_lds[3][64*40];
    __shared__ alignas(16) unsigned short v_lds[3][2048];
    int l = blockIdx.x;
    int xc = l & 7, j = l >> 3;
    int gg = xc + 8*(j/25);
    int bi = 25*gg + (j%25);
    int b = gg >> 3, h = gg & 7, qt = bi % 25;
    int tid = threadIdx.x, w = tid>>6, lane = tid&63;

    const unsigned short* ksrc = qk_t + ((size_t)(b*16+8+h)*N_SPATIAL)*32;
    const unsigned short* vms  = v_mf + (size_t)(b*200 + h*25)*2048;

    if (w < 4){
        int ql = lane&15, lg = lane>>4;
        int nq = qt*64 + w*16 + ql;
        const unsigned short* qsrc = qk_t + ((size_t)(b*16+h)*N_SPATIAL)*32;
        short8 qf = *reinterpret_cast<const short8*>(qsrc + (size_t)nq*32 + lg*8);
        f32x4 o0 = (f32x4){0.f,0.f,0.f,0.f};
        f32x4 o1 = (f32x4){0.f,0.f,0.f,0.f};
        float Sp = 0.f;

        asm volatile("" ::: "memory");
        __builtin_amdgcn_s_barrier();
        asm volatile("" ::: "memory");

        int cur = 0;
        for (int kt = 0; kt < 25; ++kt){
            const unsigned short* kb = &k_lds[cur][0];
            const unsigned short* vb = &v_lds[cur][0];
            __builtin_amdgcn_s_setprio(1);
            short8 ka0 = *reinterpret_cast<const short8*>(kb + (size_t)( 0 + ql)*40 + lg*8);
            short8 ka1 = *reinterpret_cast<const short8*>(kb + (size_t)(16 + ql)*40 + lg*8);
            short8 ka2 = *reinterpret_cast<const short8*>(kb + (size_t)(32 + ql)*40 + lg*8);
            short8 ka3 = *reinterpret_cast<const short8*>(kb + (size_t)(48 + ql)*40 + lg*8);

            f32x4 z = (f32x4){0.f,0.f,0.f,0.f};
            f32x4 p0 = __builtin_amdgcn_mfma_f32_16x16x32_bf16(ka0, qf, z, 0,0,0);
            f32x4 p1 = __builtin_amdgcn_mfma_f32_16x16x32_bf16(ka1, qf, z, 0,0,0);
            f32x4 p2 = __builtin_amdgcn_mfma_f32_16x16x32_bf16(ka2, qf, z, 0,0,0);
            f32x4 p3 = __builtin_amdgcn_mfma_f32_16x16x32_bf16(ka3, qf, z, 0,0,0);

            #pragma unroll
            for (int r=0;r<4;r++){
                p0[r] = fexp2(p0[r]);
                p1[r] = fexp2(p1[r]);
                p2[r] = fexp2(p2[r]);
                p3[r] = fexp2(p3[r]);
            }
            Sp += ((p0[0]+p0[1])+(p0[2]+p0[3])) + ((p1[0]+p1[1])+(p1[2]+p1[3]))
                + ((p2[0]+p2[1])+(p2[2]+p2[3])) + ((p3[0]+p3[1])+(p3[2]+p3[3]));

            union { int4 i; short8 s8; } pb0, pb1;
            pb0.i = make_int4((int)cvtpk(p0[0],p0[1]), (int)cvtpk(p0[2],p0[3]),
                              (int)cvtpk(p1[0],p1[1]), (int)cvtpk(p1[2],p1[3]));
            pb1.i = make_int4((int)cvtpk(p2[0],p2[1]), (int)cvtpk(p2[2],p2[3]),
                              (int)cvtpk(p3[0],p3[1]), (int)cvtpk(p3[2],p3[3]));

            short8 va0 = *reinterpret_cast<const short8*>(vb +    0 + lane*8);
            short8 va1 = *reinterpret_cast<const short8*>(vb +  512 + lane*8);
            short8 va2 = *reinterpret_cast<const short8*>(vb + 1024 + lane*8);
            short8 va3 = *reinterpret_cast<const short8*>(vb + 1536 + lane*8);

            o0 = __builtin_amdgcn_mfma_f32_16x16x32_bf16(va0, pb0.s8, o0, 0,0,0);
            o0 = __builtin_amdgcn_mfma_f32_16x16x32_bf16(va1, pb1.s8, o0, 0,0,0);
            o1 = __builtin_amdgcn_mfma_f32_16x16x32_bf16(va2, pb0.s8, o1, 0,0,0);
            o1 = __builtin_amdgcn_mfma_f32_16x16x32_bf16(va3, pb1.s8, o1, 0,0,0);
            __builtin_amdgcn_s_setprio(0);

            asm volatile("" ::: "memory");
            __builtin_amdgcn_s_barrier();
            asm volatile("" ::: "memory");
            cur = (cur==2) ? 0 : cur+1;
        }

        Sp += __shfl_xor(Sp, 16);
        Sp += __shfl_xor(Sp, 32);
        float inv = 1.f / Sp;
        size_t rowoff = ((size_t)b*N_SPATIAL + nq)*256 + h*32;
        uint2 w0 = make_uint2((unsigned)pack2(o0[0]*inv, o0[1]*inv),
                              (unsigned)pack2(o0[2]*inv, o0[3]*inv));
        *reinterpret_cast<uint2*>(ao_t + rowoff + 4*lg) = w0;
        uint2 w1 = make_uint2((unsigned)pack2(o1[0]*inv, o1[1]*inv),
                              (unsigned)pack2(o1[2]*inv, o1[3]*inv));
        *reinterpret_cast<uint2*>(ao_t + rowoff + 16 + 4*lg) = w1;
    } else {
        // 2 producer waves: thread pi stages chunks pi and pi+128 of each 4KB tile
        int pi = tid - 256;                       // [0,128)
        const unsigned short* kg0 = ksrc + pi*8;
        const unsigned short* kg1 = ksrc + (pi+128)*8;
        const unsigned short* vg0 = vms  + pi*8;
        const unsigned short* vg1 = vms  + (pi+128)*8;
        unsigned short* kd0 = &k_lds[0][0] + (pi>>2)*40 + (pi&3)*8;
        unsigned short* kd1 = kd0 + 1280;         // chunk pi+128: rows +32 -> +32*40
        unsigned short* vd0 = &v_lds[0][0] + pi*8;
        unsigned short* vd1 = vd0 + 1024;

        // prologue: tile0 -> buf0, tile1 -> buf1, tile2 held in regs
        *reinterpret_cast<int4*>(kd0) = *reinterpret_cast<const int4*>(kg0);
        *reinterpret_cast<int4*>(kd1) = *reinterpret_cast<const int4*>(kg1);
        *reinterpret_cast<int4*>(vd0) = *reinterpret_cast<const int4*>(vg0);
        *reinterpret_cast<int4*>(vd1) = *reinterpret_cast<const int4*>(vg1);
        *reinterpret_cast<int4*>(kd0 + 2560) = *reinterpret_cast<const int4*>(kg0 + 2048);
        *reinterpret_cast<int4*>(kd1 + 2560) = *reinterpret_cast<const int4*>(kg1 + 2048);
        *reinterpret_cast<int4*>(vd0 + 2048) = *reinterpret_cast<const int4*>(vg0 + 2048);
        *reinterpret_cast<int4*>(vd1 + 2048) = *reinterpret_cast<const int4*>(vg1 + 2048);
        int4 hk0 = *reinterpret_cast<const int4*>(kg0 + 4096);
        int4 hk1 = *reinterpret_cast<const int4*>(kg1 + 4096);
        int4 hv0 = *reinterpret_cast<const int4*>(vg0 + 4096);
        int4 hv1 = *reinterpret_cast<const int4*>(vg1 + 4096);
        asm volatile("s_waitcnt lgkmcnt(0)" ::: "memory");
        __builtin_amdgcn_s_barrier();
        asm volatile("" ::: "memory");

        int wb = 2;
        for (int kt = 0; kt < 25; ++kt){
            if (kt < 23){
                *reinterpret_cast<int4*>(kd0 + wb*2560) = hk0;
                *reinterpret_cast<int4*>(kd1 + wb*2560) = hk1;
                *reinterpret_cast<int4*>(vd0 + wb*2048) = hv0;
                *reinterpret_cast<int4*>(vd1 + wb*2048) = hv1;
            }
            if (kt < 22){
                hk0 = *reinterpret_cast<const int4*>(kg0 + (size_t)(kt+3)*2048);
                hk1 = *reinterpret_cast<const int4*>(kg1 + (size_t)(kt+3)*2048);
                hv0 = *reinterpret_cast<const int4*>(vg0 + (size_t)(kt+3)*2048);
                hv1 = *reinterpret_cast<const int4*>(vg1 + (size_t)(kt+3)*2048);
            }
            asm volatile("s_waitcnt lgkmcnt(0)" ::: "memory");
            __builtin_amdgcn_s_barrier();
            asm volatile("" ::: "memory");
            wb = (wb==2) ? 0 : wb+1;
        }
    }
}

// ---------------- K3: proj GEMM, 64o x 32n tiles, XCD-grouped by (b,nt) ----------------
__global__ __launch_bounds__(256) void k_proj4(const unsigned short* __restrict__ ao_t,
                                               const float* __restrict__ wp,
                                               const float* __restrict__ g,
                                               const float* __restrict__ be,
                                               const float* __restrict__ mu,
                                               const float* __restrict__ va,
                                               float* __restrict__ out){
    __shared__ alignas(16) unsigned short a_lds[64*LSTR];
    __shared__ alignas(16) unsigned short b_lds[32*LSTR];
    int l = blockIdx.x;                       // 800 = 8 * (4ot * 25ghi)
    int low3 = l & 7, inner = l >> 3;
    int ot = inner & 3, ghi = inner >> 2;     // ghi in [0,25)
    int gidx = ghi*8 + low3;                  // [0,200) = b*50 + nt
    int b = gidx/50, nt = gidx%50;
    int o0 = ot*64, n0 = nt*32;
    int tid = threadIdx.x, w = tid>>6, lane = tid&63;
    int arow = tid>>2, acol8 = (tid&3)*8;
    int brow = tid>>3, bcol4 = (tid&7)*4;
    int ql = lane&15, lg = lane>>4;
    f32x4 acc[2];
    acc[0] = (f32x4){0.f,0.f,0.f,0.f};
    acc[1] = (f32x4){0.f,0.f,0.f,0.f};
    const float* asrc = wp + (size_t)(o0+arow)*256 + acol8;
    const unsigned short* bsrc = ao_t + ((size_t)b*N_SPATIAL + n0 + brow)*256 + bcol4;
    for (int k0=0; k0<256; k0+=32){
        float4 f0 = *reinterpret_cast<const float4*>(asrc + k0);
        float4 f1 = *reinterpret_cast<const float4*>(asrc + k0 + 4);
        int4 av; av.x = pack2(f0.x,f0.y); av.y = pack2(f0.z,f0.w);
                 av.z = pack2(f1.x,f1.y); av.w = pack2(f1.z,f1.w);
        *reinterpret_cast<int4*>(&a_lds[arow*LSTR + acol8]) = av;
        *reinterpret_cast<uint2*>(&b_lds[brow*LSTR + bcol4]) = *reinterpret_cast<const uint2*>(bsrc + k0);
        __syncthreads();
        short8 af = *reinterpret_cast<const short8*>(&a_lds[(16*w + ql)*LSTR + lg*8]);
        #pragma unroll
        for (int t=0;t<2;t++){
            short8 bf = *reinterpret_cast<const short8*>(&b_lds[(16*t + ql)*LSTR + lg*8]);
            acc[t] = __builtin_amdgcn_mfma_f32_16x16x32_bf16(af, bf, acc[t], 0, 0, 0);
        }
        __syncthreads();
    }
    #pragma unroll
    for (int r=0;r<4;r++){
        int o = o0 + 16*w + lg*4 + r;
        float inv = g[o] * rsqrtf(va[o] + 1e-5f);
        float b2  = be[o] - mu[o]*inv;
        float* dst = out + ((size_t)(b*256 + o))*N_SPATIAL;
        #pragma unroll
        for (int t=0;t<2;t++){
            int n = n0 + 16*t + ql;
            float z = acc[t][r]*inv + b2;
            float y = z / (1.f + __expf(-z));
            dst[n] = y;
        }
    }
}

extern "C" void kernel_launch(void* const* d_in, const int* in_sizes, int n_in,
                              void* d_out, int out_size, void* d_ws, size_t ws_size,
                              hipStream_t stream) {
    const float* x      = (const float*)d_in[0];
    const float* qkv_w  = (const float*)d_in[1];
    const float* qkv_g  = (const float*)d_in[2];
    const float* qkv_b  = (const float*)d_in[3];
    const float* qkv_m  = (const float*)d_in[4];
    const float* qkv_v  = (const float*)d_in[5];
    const float* proj_w = (const float*)d_in[6];
    const float* proj_g = (const float*)d_in[7];
    const float* proj_b = (const float*)d_in[8];
    const float* proj_m = (const float*)d_in[9];
    const float* proj_v = (const float*)d_in[10];
    const float* pe_w   = (const float*)d_in[11];
    const float* pe_g   = (const float*)d_in[12];
    const float* pe_b   = (const float*)d_in[13];
    const float* pe_m   = (const float*)d_in[14];
    const float* pe_v   = (const float*)d_in[15];

    char* ws = (char*)d_ws;
    unsigned short* v_mf = (unsigned short*)(ws);                 // 3,276,800
    unsigned short* qk_t = (unsigned short*)(ws + 3276800);       // 6,553,600
    unsigned short* ao_t = (unsigned short*)(ws + 9830400);       // 3,276,800
    float* outp = (float*)d_out;

    k_fuse <<<1632,256, 0, stream>>>(x, qkv_w, qkv_g, qkv_b, qkv_m, qkv_v,
                                     pe_w, pe_g, pe_b, pe_m, pe_v, qk_t, v_mf);
    k_attn7<<<800, 384, 0, stream>>>(qk_t, v_mf, ao_t);
    k_proj4<<<800, 256, 0, stream>>>(ao_t, proj_w, proj_g, proj_b, proj_m, proj_v, outp);
}